// Round 1
// baseline (1818.845 us; speedup 1.0000x reference)
//
#include <hip/hip_runtime.h>

#define D 256
#define N0C 100000
#define N1C 20000
#define N2C 4000

typedef short s16x8 __attribute__((ext_vector_type(8)));
typedef float f32x4 __attribute__((ext_vector_type(4)));

__device__ __forceinline__ short f2bf(float f) {
  unsigned u = __float_as_uint(f);
  u += 0x7fff + ((u >> 16) & 1);   // round-nearest-even
  return (short)(u >> 16);
}
__device__ __forceinline__ float bf2f(short s) {
  return __uint_as_float(((unsigned)(unsigned short)s) << 16);
}

// W (K=256, N=256) row-major f32  ->  WT (N,K) row-major bf16
__global__ __launch_bounds__(256) void wtrans_k(const float* __restrict__ W,
                                                short* __restrict__ WT) {
  int k = blockIdx.x, n = threadIdx.x;
  WT[n * D + k] = f2bf(W[k * D + n]);
}

// out = relu( A1 @ B1T^T [+ A2 @ B2T^T] + bias ), A fp32 MxK(K=256), BT bf16 NxK(N=256)
// Per wave: 32 rows x 32 cols via 2x2 16x16 tiles.  Block = 4 waves = 32 rows x 128 cols.
// grid = (M/32, 2)
template<int NSRC, int BF16OUT>
__global__ __launch_bounds__(256) void gemm_k(
    const float* __restrict__ A1, const short* __restrict__ B1T,
    const float* __restrict__ A2, const short* __restrict__ B2T,
    const float* __restrict__ bias, void* __restrict__ outp)
{
  int wave = threadIdx.x >> 6, lane = threadIdx.x & 63;
  int m_base = blockIdx.x * 32;
  int n_base = blockIdx.y * 128 + wave * 32;
  int lr = lane & 15;   // A-row / B-col / D-col within 16-tile
  int kg = lane >> 4;   // k-group (0..3)
  int kl = kg * 8;      // k offset within 32-chunk

  f32x4 acc[2][2];
  for (int t = 0; t < 2; t++)
    for (int u = 0; u < 2; u++)
      acc[t][u] = (f32x4)(0.0f);

  const float* As[2] = {A1, A2};
  const short* Bs[2] = {B1T, B2T};

  for (int sidx = 0; sidx < NSRC; ++sidx) {
    const float* A  = As[sidx];
    const short* BT = Bs[sidx];
    for (int k0 = 0; k0 < D; k0 += 32) {
      s16x8 a[2], b[2];
      for (int t = 0; t < 2; t++) {
        const float* ap = A + (size_t)(m_base + t * 16 + lr) * D + k0 + kl;
        float4 f0 = *(const float4*)ap;
        float4 f1 = *(const float4*)(ap + 4);
        a[t][0] = f2bf(f0.x); a[t][1] = f2bf(f0.y);
        a[t][2] = f2bf(f0.z); a[t][3] = f2bf(f0.w);
        a[t][4] = f2bf(f1.x); a[t][5] = f2bf(f1.y);
        a[t][6] = f2bf(f1.z); a[t][7] = f2bf(f1.w);
      }
      for (int u = 0; u < 2; u++)
        b[u] = *(const s16x8*)(Bs[sidx] + (size_t)(n_base + u * 16 + lr) * D + k0 + kl);
      for (int t = 0; t < 2; t++)
        for (int u = 0; u < 2; u++)
          acc[t][u] = __builtin_amdgcn_mfma_f32_16x16x32_bf16(a[t], b[u], acc[t][u], 0, 0, 0);
      (void)A; (void)BT;
    }
  }

  // D layout: col = lane&15, row = (lane>>4)*4 + i   [verified mapping]
  for (int t = 0; t < 2; t++)
    for (int u = 0; u < 2; u++) {
      int c = n_base + u * 16 + lr;
      float bv = bias[c];
      int rbase = m_base + t * 16 + kg * 4;
      for (int i = 0; i < 4; i++) {
        float v = acc[t][u][i] + bv;
        v = v > 0.0f ? v : 0.0f;
        size_t idx = (size_t)(rbase + i) * D + c;
        if (BF16OUT) ((short*)outp)[idx] = f2bf(v);
        else         ((float*)outp)[idx] = v;
      }
    }
}

// agg[dst[e]][d] = max over edges of h[src[e]][d] * w[e]   (all values >= 0,
// agg zero-initialized -> float-as-int atomicMax is exact, empty segs -> 0)
__global__ __launch_bounds__(256) void edge_max_k(
    const short* __restrict__ h, const int* __restrict__ src,
    const int* __restrict__ dst, const float* __restrict__ w,
    int* __restrict__ agg, int E)
{
  int e = blockIdx.x * 4 + (threadIdx.x >> 6);
  if (e >= E) return;
  int lane = threadIdx.x & 63;
  int s = src[e], d = dst[e];
  float we = w[e];
  short4 hv = *(const short4*)(h + (size_t)s * D + lane * 4);
  int* ap = agg + (size_t)d * D + lane * 4;
  float v;
  v = bf2f(hv.x) * we; atomicMax(ap + 0, __float_as_int(v));
  v = bf2f(hv.y) * we; atomicMax(ap + 1, __float_as_int(v));
  v = bf2f(hv.z) * we; atomicMax(ap + 2, __float_as_int(v));
  v = bf2f(hv.w) * we; atomicMax(ap + 3, __float_as_int(v));
}

extern "C" void kernel_launch(void* const* d_in, const int* in_sizes, int n_in,
                              void* d_out, int out_size, void* d_ws, size_t ws_size,
                              hipStream_t stream)
{
  const float* x   = (const float*)d_in[0];
  const int*   src0 = (const int*)d_in[1];
  const int*   dst0 = (const int*)d_in[2];
  const float* w0  = (const float*)d_in[3];
  const int*   src1 = (const int*)d_in[4];
  const int*   dst1 = (const int*)d_in[5];
  const float* w1  = (const float*)d_in[6];
  const float* Wp1 = (const float*)d_in[7];
  const float* bp1 = (const float*)d_in[8];
  const float* Ws1 = (const float*)d_in[9];
  const float* Wn1 = (const float*)d_in[10];
  const float* b1  = (const float*)d_in[11];
  const float* Wp2 = (const float*)d_in[12];
  const float* bp2 = (const float*)d_in[13];
  const float* Ws2 = (const float*)d_in[14];
  const float* Wn2 = (const float*)d_in[15];
  const float* b2  = (const float*)d_in[16];

  const int E0 = in_sizes[1], E1 = in_sizes[4];

  char* ws = (char*)d_ws;
  size_t off = 0;
  auto alloc = [&](size_t bytes) {
    void* p = ws + off;
    off += (bytes + 255) & ~(size_t)255;
    return p;
  };
  short* wp1t = (short*)alloc((size_t)D * D * 2);
  short* ws1t = (short*)alloc((size_t)D * D * 2);
  short* wn1t = (short*)alloc((size_t)D * D * 2);
  short* wp2t = (short*)alloc((size_t)D * D * 2);
  short* ws2t = (short*)alloc((size_t)D * D * 2);
  short* wn2t = (short*)alloc((size_t)D * D * 2);
  short* h1   = (short*)alloc((size_t)N0C * D * 2);
  short* h2   = (short*)alloc((size_t)N1C * D * 2);
  int*   agg1 = (int*)alloc((size_t)N1C * D * 4);
  int*   agg2 = (int*)alloc((size_t)N2C * D * 4);
  float* l1o  = (float*)alloc((size_t)N1C * D * 4);

  hipMemsetAsync(agg1, 0, (size_t)N1C * D * 4, stream);
  hipMemsetAsync(agg2, 0, (size_t)N2C * D * 4, stream);

  wtrans_k<<<D, D, 0, stream>>>(Wp1, wp1t);
  wtrans_k<<<D, D, 0, stream>>>(Ws1, ws1t);
  wtrans_k<<<D, D, 0, stream>>>(Wn1, wn1t);
  wtrans_k<<<D, D, 0, stream>>>(Wp2, wp2t);
  wtrans_k<<<D, D, 0, stream>>>(Ws2, ws2t);
  wtrans_k<<<D, D, 0, stream>>>(Wn2, wn2t);

  // h1 = relu(x @ Wp1 + bp1)  -> bf16
  gemm_k<1, 1><<<dim3(N0C / 32, 2), 256, 0, stream>>>(x, wp1t, nullptr, nullptr, bp1, h1);
  // agg1 = segment_max(h1[src0]*w0, dst0)
  edge_max_k<<<(E0 + 3) / 4, 256, 0, stream>>>(h1, src0, dst0, w0, agg1, E0);
  // l1o = relu(x[:N1] @ Ws1 + agg1 @ Wn1 + b1)
  gemm_k<2, 0><<<dim3(N1C / 32, 2), 256, 0, stream>>>(x, ws1t, (const float*)agg1, wn1t, b1, l1o);
  // h2 = relu(l1o @ Wp2 + bp2) -> bf16
  gemm_k<1, 1><<<dim3(N1C / 32, 2), 256, 0, stream>>>(l1o, wp2t, nullptr, nullptr, bp2, h2);
  // agg2 = segment_max(h2[src1]*w1, dst1)
  edge_max_k<<<(E1 + 3) / 4, 256, 0, stream>>>(h2, src1, dst1, w1, agg2, E1);
  // out = relu(l1o[:N2] @ Ws2 + agg2 @ Wn2 + b2)
  gemm_k<2, 0><<<dim3(N2C / 32, 2), 256, 0, stream>>>(l1o, ws2t, (const float*)agg2, wn2t, b2, d_out);
}

// Round 2
// 380.763 us; speedup vs baseline: 4.7768x; 4.7768x over previous
//
#include <hip/hip_runtime.h>

#define D 256
#define N0C 100000
#define N1C 20000
#define N2C 4000

typedef short s16x8 __attribute__((ext_vector_type(8)));
typedef float f32x4 __attribute__((ext_vector_type(4)));

__device__ __forceinline__ short f2bf(float f) {
  unsigned u = __float_as_uint(f);
  u += 0x7fff + ((u >> 16) & 1);   // round-nearest-even
  return (short)(u >> 16);
}
__device__ __forceinline__ float bf2f(short s) {
  return __uint_as_float(((unsigned)(unsigned short)s) << 16);
}

// ---- weight transpose: 6x  W(K,N) f32 row-major -> WT(N,K) bf16 row-major
__global__ __launch_bounds__(256) void wtrans6_k(
    const float* __restrict__ W0, const float* __restrict__ W1,
    const float* __restrict__ W2, const float* __restrict__ W3,
    const float* __restrict__ W4, const float* __restrict__ W5,
    short* __restrict__ T0, short* __restrict__ T1, short* __restrict__ T2,
    short* __restrict__ T3, short* __restrict__ T4, short* __restrict__ T5)
{
  const float* Ws[6] = {W0, W1, W2, W3, W4, W5};
  short* Ts[6] = {T0, T1, T2, T3, T4, T5};
  int g = blockIdx.y, k = blockIdx.x, n = threadIdx.x;
  Ts[g][n * D + k] = f2bf(Ws[g][k * D + n]);
}

// ---- CSR build: histogram of dst (both graphs in one launch)
__global__ __launch_bounds__(256) void hist_k(
    const int* __restrict__ dst0, int E0, int* __restrict__ c0,
    const int* __restrict__ dst1, int E1, int* __restrict__ c1)
{
  int i = blockIdx.x * 256 + threadIdx.x;
  if (i < E0) atomicAdd(&c0[dst0[i]], 1);
  else if (i < E0 + E1) atomicAdd(&c1[dst1[i - E0]], 1);
}

// ---- exclusive scan, one block per graph (block 0: graph0, block 1: graph1)
__global__ __launch_bounds__(256) void scan_k(
    const int* __restrict__ c0, int* __restrict__ o0, int n0,
    const int* __restrict__ c1, int* __restrict__ o1, int n1)
{
  const int* c = blockIdx.x ? c1 : c0;
  int* o = blockIdx.x ? o1 : o0;
  int n = blockIdx.x ? n1 : n0;
  __shared__ int lsum[256];
  int t = threadIdx.x;
  int chunk = (n + 255) / 256;
  int beg = t * chunk, end = min(beg + chunk, n);
  int s = 0;
  for (int i = beg; i < end; ++i) s += c[i];
  lsum[t] = s;
  __syncthreads();
  for (int d = 1; d < 256; d <<= 1) {
    int v = (t >= d) ? lsum[t - d] : 0;
    __syncthreads();
    lsum[t] += v;
    __syncthreads();
  }
  int run = (t == 0) ? 0 : lsum[t - 1];
  for (int i = beg; i < end; ++i) { o[i] = run; run += c[i]; }
  if (t == 255) o[n] = run;
}

// ---- scatter edges into dst-sorted (src, w) arrays
__global__ __launch_bounds__(256) void scat_k(
    const int* __restrict__ src0, const int* __restrict__ dst0,
    const float* __restrict__ w0, int E0, const int* __restrict__ offs0,
    int* __restrict__ cur0, int* __restrict__ ss0, float* __restrict__ ws0,
    const int* __restrict__ src1, const int* __restrict__ dst1,
    const float* __restrict__ w1, int E1, const int* __restrict__ offs1,
    int* __restrict__ cur1, int* __restrict__ ss1, float* __restrict__ ws1)
{
  int i = blockIdx.x * 256 + threadIdx.x;
  if (i < E0) {
    int d = dst0[i];
    int p = offs0[d] + atomicAdd(&cur0[d], 1);
    ss0[p] = src0[i]; ws0[p] = w0[i];
  } else if (i < E0 + E1) {
    int j = i - E0;
    int d = dst1[j];
    int p = offs1[d] + atomicAdd(&cur1[d], 1);
    ss1[p] = src1[j]; ws1[p] = w1[j];
  }
}

// ---- per-dst gather max: one wave per dst node, 64 lanes x 4 dims
//      all msgs >= 0 (h=relu, w in [0,1)) -> init 0 matches empty-seg rule
__global__ __launch_bounds__(256) void seg_max_k(
    const short* __restrict__ h, const int* __restrict__ offs,
    const int* __restrict__ src_s, const float* __restrict__ w_s,
    short* __restrict__ agg, int ndst)
{
  int dst = blockIdx.x * 4 + (threadIdx.x >> 6);
  if (dst >= ndst) return;
  int lane = threadIdx.x & 63;
  int beg = offs[dst], end = offs[dst + 1];
  float m0 = 0.f, m1 = 0.f, m2 = 0.f, m3 = 0.f;
  const short* hp = h + (size_t)lane * 4;
  for (int i = beg; i < end; ++i) {
    int s = src_s[i];
    float we = w_s[i];
    short4 hv = *(const short4*)(hp + (size_t)s * D);
    m0 = fmaxf(m0, bf2f(hv.x) * we);
    m1 = fmaxf(m1, bf2f(hv.y) * we);
    m2 = fmaxf(m2, bf2f(hv.z) * we);
    m3 = fmaxf(m3, bf2f(hv.w) * we);
  }
  short4 o;
  o.x = f2bf(m0); o.y = f2bf(m1); o.z = f2bf(m2); o.w = f2bf(m3);
  *(short4*)(agg + (size_t)dst * D + lane * 4) = o;
}

// ---- GEMM: out = relu( A1 @ B1T^T [+ A2 @ B2T^T] + bias )
// A (M x 256) fp32 or bf16; BT bf16 (256 x 256) N-major.
// wave: 32 rows x 64 cols (2x4 16x16 tiles); block: 4 waves side-by-side
// covering all 256 cols; grid = M/32.
__device__ __forceinline__ s16x8 load8(const float* p) {
  float4 f0 = *(const float4*)p;
  float4 f1 = *(const float4*)(p + 4);
  s16x8 r;
  r[0] = f2bf(f0.x); r[1] = f2bf(f0.y); r[2] = f2bf(f0.z); r[3] = f2bf(f0.w);
  r[4] = f2bf(f1.x); r[5] = f2bf(f1.y); r[6] = f2bf(f1.z); r[7] = f2bf(f1.w);
  return r;
}
__device__ __forceinline__ s16x8 load8(const short* p) {
  return *(const s16x8*)p;
}

template<typename TA1, typename TA2, int NSRC, int F32OUT>
__global__ __launch_bounds__(256) void gemm_k(
    const TA1* __restrict__ A1, const short* __restrict__ B1T,
    const TA2* __restrict__ A2, const short* __restrict__ B2T,
    const float* __restrict__ bias, void* __restrict__ outp)
{
  int wave = threadIdx.x >> 6, lane = threadIdx.x & 63;
  int m_base = blockIdx.x * 32;
  int n_base = wave * 64;
  int lr = lane & 15;   // row within A-tile / col within B/D-tile
  int kg = lane >> 4;   // k-group
  int kl = kg * 8;

  f32x4 acc[2][4];
  for (int t = 0; t < 2; t++)
    for (int u = 0; u < 4; u++)
      acc[t][u] = (f32x4)(0.0f);

  for (int k0 = 0; k0 < D; k0 += 32) {
    s16x8 a[2], b[4];
    for (int t = 0; t < 2; t++)
      a[t] = load8(A1 + (size_t)(m_base + t * 16 + lr) * D + k0 + kl);
    for (int u = 0; u < 4; u++)
      b[u] = *(const s16x8*)(B1T + (size_t)(n_base + u * 16 + lr) * D + k0 + kl);
    for (int t = 0; t < 2; t++)
      for (int u = 0; u < 4; u++)
        acc[t][u] = __builtin_amdgcn_mfma_f32_16x16x32_bf16(a[t], b[u], acc[t][u], 0, 0, 0);
  }
  if (NSRC == 2) {
    for (int k0 = 0; k0 < D; k0 += 32) {
      s16x8 a[2], b[4];
      for (int t = 0; t < 2; t++)
        a[t] = load8(A2 + (size_t)(m_base + t * 16 + lr) * D + k0 + kl);
      for (int u = 0; u < 4; u++)
        b[u] = *(const s16x8*)(B2T + (size_t)(n_base + u * 16 + lr) * D + k0 + kl);
      for (int t = 0; t < 2; t++)
        for (int u = 0; u < 4; u++)
          acc[t][u] = __builtin_amdgcn_mfma_f32_16x16x32_bf16(a[t], b[u], acc[t][u], 0, 0, 0);
    }
  }

  // D layout: col = lane&15, row = (lane>>4)*4 + i
  for (int t = 0; t < 2; t++)
    for (int u = 0; u < 4; u++) {
      int c = n_base + u * 16 + lr;
      float bv = bias[c];
      int rbase = m_base + t * 16 + kg * 4;
      for (int i = 0; i < 4; i++) {
        float v = acc[t][u][i] + bv;
        v = v > 0.0f ? v : 0.0f;
        size_t idx = (size_t)(rbase + i) * D + c;
        if (F32OUT) ((float*)outp)[idx] = v;
        else        ((short*)outp)[idx] = f2bf(v);
      }
    }
}

extern "C" void kernel_launch(void* const* d_in, const int* in_sizes, int n_in,
                              void* d_out, int out_size, void* d_ws, size_t ws_size,
                              hipStream_t stream)
{
  const float* x    = (const float*)d_in[0];
  const int*   src0 = (const int*)d_in[1];
  const int*   dst0 = (const int*)d_in[2];
  const float* w0   = (const float*)d_in[3];
  const int*   src1 = (const int*)d_in[4];
  const int*   dst1 = (const int*)d_in[5];
  const float* w1   = (const float*)d_in[6];
  const float* Wp1  = (const float*)d_in[7];
  const float* bp1  = (const float*)d_in[8];
  const float* Ws1  = (const float*)d_in[9];
  const float* Wn1  = (const float*)d_in[10];
  const float* b1   = (const float*)d_in[11];
  const float* Wp2  = (const float*)d_in[12];
  const float* bp2  = (const float*)d_in[13];
  const float* Ws2  = (const float*)d_in[14];
  const float* Wn2  = (const float*)d_in[15];
  const float* b2   = (const float*)d_in[16];

  const int E0 = in_sizes[1], E1 = in_sizes[4];

  char* ws = (char*)d_ws;
  size_t off = 0;
  auto alloc = [&](size_t bytes) {
    void* p = ws + off;
    off += (bytes + 255) & ~(size_t)255;
    return p;
  };
  short* wp1t = (short*)alloc((size_t)D * D * 2);
  short* ws1t = (short*)alloc((size_t)D * D * 2);
  short* wn1t = (short*)alloc((size_t)D * D * 2);
  short* wp2t = (short*)alloc((size_t)D * D * 2);
  short* ws2t = (short*)alloc((size_t)D * D * 2);
  short* wn2t = (short*)alloc((size_t)D * D * 2);
  short* h1   = (short*)alloc((size_t)N0C * D * 2);
  short* h2   = (short*)alloc((size_t)N1C * D * 2);
  short* l1o  = (short*)alloc((size_t)N1C * D * 2);
  short* agg1 = (short*)alloc((size_t)N1C * D * 2);
  short* agg2 = (short*)alloc((size_t)N2C * D * 2);
  int*   cnt0 = (int*)alloc((size_t)N1C * 4);
  int*   cur0 = (int*)alloc((size_t)N1C * 4);
  int*   off0 = (int*)alloc((size_t)(N1C + 1) * 4);
  int*   cnt1 = (int*)alloc((size_t)N2C * 4);
  int*   cur1 = (int*)alloc((size_t)N2C * 4);
  int*   off1 = (int*)alloc((size_t)(N2C + 1) * 4);
  int*   ss0  = (int*)alloc((size_t)E0 * 4);
  float* wss0 = (float*)alloc((size_t)E0 * 4);
  int*   ss1  = (int*)alloc((size_t)E1 * 4);
  float* wss1 = (float*)alloc((size_t)E1 * 4);

  hipMemsetAsync(cnt0, 0, (size_t)N1C * 4, stream);
  hipMemsetAsync(cur0, 0, (size_t)N1C * 4, stream);
  hipMemsetAsync(cnt1, 0, (size_t)N2C * 4, stream);
  hipMemsetAsync(cur1, 0, (size_t)N2C * 4, stream);

  wtrans6_k<<<dim3(D, 6), D, 0, stream>>>(Wp1, Ws1, Wn1, Wp2, Ws2, Wn2,
                                          wp1t, ws1t, wn1t, wp2t, ws2t, wn2t);

  int eb = (E0 + E1 + 255) / 256;
  hist_k<<<eb, 256, 0, stream>>>(dst0, E0, cnt0, dst1, E1, cnt1);
  scan_k<<<2, 256, 0, stream>>>(cnt0, off0, N1C, cnt1, off1, N2C);
  scat_k<<<eb, 256, 0, stream>>>(src0, dst0, w0, E0, off0, cur0, ss0, wss0,
                                 src1, dst1, w1, E1, off1, cur1, ss1, wss1);

  // h1 = relu(x @ Wp1 + bp1) -> bf16
  gemm_k<float, short, 1, 0><<<N0C / 32, 256, 0, stream>>>(x, wp1t, (const short*)nullptr, nullptr, bp1, h1);
  // agg1 = segment_max(h1[src0]*w0, dst0) -> bf16
  seg_max_k<<<(N1C + 3) / 4, 256, 0, stream>>>(h1, off0, ss0, wss0, agg1, N1C);
  // l1o = relu(x[:N1] @ Ws1 + agg1 @ Wn1 + b1) -> bf16
  gemm_k<float, short, 2, 0><<<N1C / 32, 256, 0, stream>>>(x, ws1t, agg1, wn1t, b1, l1o);
  // h2 = relu(l1o @ Wp2 + bp2) -> bf16
  gemm_k<short, short, 1, 0><<<N1C / 32, 256, 0, stream>>>(l1o, wp2t, (const short*)nullptr, nullptr, bp2, h2);
  // agg2 = segment_max(h2[src1]*w1, dst1) -> bf16
  seg_max_k<<<(N2C + 3) / 4, 256, 0, stream>>>(h2, off1, ss1, wss1, agg2, N2C);
  // out = relu(l1o[:N2] @ Ws2 + agg2 @ Wn2 + b2) -> fp32
  gemm_k<short, short, 2, 1><<<N2C / 32, 256, 0, stream>>>(l1o, ws2t, agg2, wn2t, b2, d_out);
}

// Round 3
// 364.338 us; speedup vs baseline: 4.9922x; 1.0451x over previous
//
#include <hip/hip_runtime.h>
#include <hip/hip_bf16.h>

#define D 256
#define N0C 100000
#define N1C 20000
#define N2C 4000

typedef short s16x8 __attribute__((ext_vector_type(8)));
typedef float f32x4 __attribute__((ext_vector_type(4)));

__device__ __forceinline__ short f2bf(float f) {
  __hip_bfloat16 b = __float2bfloat16(f);   // RNE hardware cvt (fuses to v_cvt_pk_bf16_f32)
  union { __hip_bfloat16 h; short s; } u;
  u.h = b;
  return u.s;
}
__device__ __forceinline__ float bf2f(short s) {
  return __uint_as_float(((unsigned)(unsigned short)s) << 16);
}

// ---- weight transpose: 6x  W(K,N) f32 row-major -> WT(N,K) bf16 row-major
__global__ __launch_bounds__(256) void wtrans6_k(
    const float* __restrict__ W0, const float* __restrict__ W1,
    const float* __restrict__ W2, const float* __restrict__ W3,
    const float* __restrict__ W4, const float* __restrict__ W5,
    short* __restrict__ T0, short* __restrict__ T1, short* __restrict__ T2,
    short* __restrict__ T3, short* __restrict__ T4, short* __restrict__ T5)
{
  const float* Ws[6] = {W0, W1, W2, W3, W4, W5};
  short* Ts[6] = {T0, T1, T2, T3, T4, T5};
  int g = blockIdx.y, k = blockIdx.x, n = threadIdx.x;
  Ts[g][n * D + k] = f2bf(Ws[g][k * D + n]);
}

// ---- CSR build
__global__ __launch_bounds__(256) void hist_k(
    const int* __restrict__ dst0, int E0, int* __restrict__ c0,
    const int* __restrict__ dst1, int E1, int* __restrict__ c1)
{
  int i = blockIdx.x * 256 + threadIdx.x;
  if (i < E0) atomicAdd(&c0[dst0[i]], 1);
  else if (i < E0 + E1) atomicAdd(&c1[dst1[i - E0]], 1);
}

__global__ __launch_bounds__(256) void scan_k(
    const int* __restrict__ c0, int* __restrict__ o0, int n0,
    const int* __restrict__ c1, int* __restrict__ o1, int n1)
{
  const int* c = blockIdx.x ? c1 : c0;
  int* o = blockIdx.x ? o1 : o0;
  int n = blockIdx.x ? n1 : n0;
  __shared__ int lsum[256];
  int t = threadIdx.x;
  int chunk = (n + 255) / 256;
  int beg = t * chunk, end = min(beg + chunk, n);
  int s = 0;
  for (int i = beg; i < end; ++i) s += c[i];
  lsum[t] = s;
  __syncthreads();
  for (int d = 1; d < 256; d <<= 1) {
    int v = (t >= d) ? lsum[t - d] : 0;
    __syncthreads();
    lsum[t] += v;
    __syncthreads();
  }
  int run = (t == 0) ? 0 : lsum[t - 1];
  for (int i = beg; i < end; ++i) { o[i] = run; run += c[i]; }
  if (t == 255) o[n] = run;
}

__global__ __launch_bounds__(256) void scat_k(
    const int* __restrict__ src0, const int* __restrict__ dst0,
    const float* __restrict__ w0, int E0, const int* __restrict__ offs0,
    int* __restrict__ cur0, int* __restrict__ ss0, float* __restrict__ ws0,
    const int* __restrict__ src1, const int* __restrict__ dst1,
    const float* __restrict__ w1, int E1, const int* __restrict__ offs1,
    int* __restrict__ cur1, int* __restrict__ ss1, float* __restrict__ ws1)
{
  int i = blockIdx.x * 256 + threadIdx.x;
  if (i < E0) {
    int d = dst0[i];
    int p = offs0[d] + atomicAdd(&cur0[d], 1);
    ss0[p] = src0[i]; ws0[p] = w0[i];
  } else if (i < E0 + E1) {
    int j = i - E0;
    int d = dst1[j];
    int p = offs1[d] + atomicAdd(&cur1[d], 1);
    ss1[p] = src1[j]; ws1[p] = w1[j];
  }
}

// ---- per-dst gather max, 2-edge unrolled for load ILP
__global__ __launch_bounds__(256) void seg_max_k(
    const short* __restrict__ h, const int* __restrict__ offs,
    const int* __restrict__ src_s, const float* __restrict__ w_s,
    short* __restrict__ agg, int ndst)
{
  int dst = blockIdx.x * 4 + (threadIdx.x >> 6);
  if (dst >= ndst) return;
  int lane = threadIdx.x & 63;
  int beg = offs[dst], end = offs[dst + 1];
  const short* hp = h + (size_t)lane * 4;
  float a0 = 0.f, a1 = 0.f, a2 = 0.f, a3 = 0.f;
  float b0 = 0.f, b1 = 0.f, b2 = 0.f, b3 = 0.f;
  int i = beg;
  for (; i + 1 < end; i += 2) {
    int sA = src_s[i], sB = src_s[i + 1];
    float wA = w_s[i], wB = w_s[i + 1];
    short4 hA = *(const short4*)(hp + (size_t)sA * D);
    short4 hB = *(const short4*)(hp + (size_t)sB * D);
    a0 = fmaxf(a0, bf2f(hA.x) * wA); a1 = fmaxf(a1, bf2f(hA.y) * wA);
    a2 = fmaxf(a2, bf2f(hA.z) * wA); a3 = fmaxf(a3, bf2f(hA.w) * wA);
    b0 = fmaxf(b0, bf2f(hB.x) * wB); b1 = fmaxf(b1, bf2f(hB.y) * wB);
    b2 = fmaxf(b2, bf2f(hB.z) * wB); b3 = fmaxf(b3, bf2f(hB.w) * wB);
  }
  if (i < end) {
    int sA = src_s[i];
    float wA = w_s[i];
    short4 hA = *(const short4*)(hp + (size_t)sA * D);
    a0 = fmaxf(a0, bf2f(hA.x) * wA); a1 = fmaxf(a1, bf2f(hA.y) * wA);
    a2 = fmaxf(a2, bf2f(hA.z) * wA); a3 = fmaxf(a3, bf2f(hA.w) * wA);
  }
  short4 o;
  o.x = f2bf(fmaxf(a0, b0)); o.y = f2bf(fmaxf(a1, b1));
  o.z = f2bf(fmaxf(a2, b2)); o.w = f2bf(fmaxf(a3, b3));
  *(short4*)(agg + (size_t)dst * D + lane * 4) = o;
}

// ---- GEMM helpers: raw (pre-cvt) fragment load, then cvt to bf16 frag
struct Raw8f { float4 lo, hi; };
__device__ __forceinline__ Raw8f loadraw(const float* p) {
  Raw8f r;
  r.lo = *(const float4*)p;
  r.hi = *(const float4*)(p + 4);
  return r;
}
__device__ __forceinline__ s16x8 loadraw(const short* p) {
  return *(const s16x8*)p;
}
__device__ __forceinline__ s16x8 cvtfrag(const Raw8f& r) {
  s16x8 a;
  a[0] = f2bf(r.lo.x); a[1] = f2bf(r.lo.y); a[2] = f2bf(r.lo.z); a[3] = f2bf(r.lo.w);
  a[4] = f2bf(r.hi.x); a[5] = f2bf(r.hi.y); a[6] = f2bf(r.hi.z); a[7] = f2bf(r.hi.w);
  return a;
}
__device__ __forceinline__ s16x8 cvtfrag(const s16x8& r) { return r; }

// one K=256 segment, software-pipelined 1 deep, fully unrolled
template<typename TA>
__device__ __forceinline__ void gemm_seg(
    const TA* __restrict__ A, const short* __restrict__ BT,
    const int* rowc, int n_base, int lr, int kl, f32x4 (&acc)[4][4])
{
  using RawT = decltype(loadraw(A));
  RawT ar[4], arn[4];
  s16x8 b[4], bn[4];
#pragma unroll
  for (int t = 0; t < 4; t++) ar[t] = loadraw(A + (size_t)rowc[t] * D + kl);
#pragma unroll
  for (int u = 0; u < 4; u++) b[u] = *(const s16x8*)(BT + (size_t)(n_base + u * 16 + lr) * D + kl);
#pragma unroll
  for (int k0 = 0; k0 < D; k0 += 32) {
    if (k0 + 32 < D) {
#pragma unroll
      for (int t = 0; t < 4; t++) arn[t] = loadraw(A + (size_t)rowc[t] * D + k0 + 32 + kl);
#pragma unroll
      for (int u = 0; u < 4; u++) bn[u] = *(const s16x8*)(BT + (size_t)(n_base + u * 16 + lr) * D + k0 + 32 + kl);
    }
    s16x8 a[4];
#pragma unroll
    for (int t = 0; t < 4; t++) a[t] = cvtfrag(ar[t]);
#pragma unroll
    for (int t = 0; t < 4; t++)
#pragma unroll
      for (int u = 0; u < 4; u++)
        acc[t][u] = __builtin_amdgcn_mfma_f32_16x16x32_bf16(a[t], b[u], acc[t][u], 0, 0, 0);
    if (k0 + 32 < D) {
#pragma unroll
      for (int t = 0; t < 4; t++) ar[t] = arn[t];
#pragma unroll
      for (int u = 0; u < 4; u++) b[u] = bn[u];
    }
  }
}

// out = relu( A1 @ B1T^T [+ A2 @ B2T^T] + bias ), per wave 64 rows x 64 cols
// block = 4 waves side-by-side = 64 rows x 256 cols; grid = ceil(M/64)
template<typename TA1, typename TA2, int NSRC, int F32OUT>
__global__ __launch_bounds__(256, 3) void gemm_k(
    const TA1* __restrict__ A1, const short* __restrict__ B1T,
    const TA2* __restrict__ A2, const short* __restrict__ B2T,
    const float* __restrict__ bias, void* __restrict__ outp, int M)
{
  int wave = threadIdx.x >> 6, lane = threadIdx.x & 63;
  int m_base = blockIdx.x * 64;
  int n_base = wave * 64;
  int lr = lane & 15;
  int kg = lane >> 4;
  int kl = kg * 8;

  f32x4 acc[4][4];
#pragma unroll
  for (int t = 0; t < 4; t++)
#pragma unroll
    for (int u = 0; u < 4; u++) acc[t][u] = (f32x4)(0.0f);

  int rowc[4];
#pragma unroll
  for (int t = 0; t < 4; t++) {
    int r = m_base + t * 16 + lr;
    rowc[t] = r < M ? r : M - 1;
  }

  gemm_seg(A1, B1T, rowc, n_base, lr, kl, acc);
  if (NSRC == 2) gemm_seg(A2, B2T, rowc, n_base, lr, kl, acc);

  bool tail = (m_base + 64 > M);
#pragma unroll
  for (int t = 0; t < 4; t++)
#pragma unroll
    for (int u = 0; u < 4; u++) {
      int c = n_base + u * 16 + lr;
      float bv = bias[c];
      int rbase = m_base + t * 16 + kg * 4;
#pragma unroll
      for (int i = 0; i < 4; i++) {
        int r = rbase + i;
        if (tail && r >= M) continue;
        float v = acc[t][u][i] + bv;
        v = v > 0.0f ? v : 0.0f;
        size_t idx = (size_t)r * D + c;
        if (F32OUT) ((float*)outp)[idx] = v;
        else        ((short*)outp)[idx] = f2bf(v);
      }
    }
}

extern "C" void kernel_launch(void* const* d_in, const int* in_sizes, int n_in,
                              void* d_out, int out_size, void* d_ws, size_t ws_size,
                              hipStream_t stream)
{
  const float* x    = (const float*)d_in[0];
  const int*   src0 = (const int*)d_in[1];
  const int*   dst0 = (const int*)d_in[2];
  const float* w0   = (const float*)d_in[3];
  const int*   src1 = (const int*)d_in[4];
  const int*   dst1 = (const int*)d_in[5];
  const float* w1   = (const float*)d_in[6];
  const float* Wp1  = (const float*)d_in[7];
  const float* bp1  = (const float*)d_in[8];
  const float* Ws1  = (const float*)d_in[9];
  const float* Wn1  = (const float*)d_in[10];
  const float* b1   = (const float*)d_in[11];
  const float* Wp2  = (const float*)d_in[12];
  const float* bp2  = (const float*)d_in[13];
  const float* Ws2  = (const float*)d_in[14];
  const float* Wn2  = (const float*)d_in[15];
  const float* b2   = (const float*)d_in[16];

  const int E0 = in_sizes[1], E1 = in_sizes[4];

  char* ws = (char*)d_ws;
  size_t off = 0;
  auto alloc = [&](size_t bytes) {
    void* p = ws + off;
    off += (bytes + 255) & ~(size_t)255;
    return p;
  };
  short* wp1t = (short*)alloc((size_t)D * D * 2);
  short* ws1t = (short*)alloc((size_t)D * D * 2);
  short* wn1t = (short*)alloc((size_t)D * D * 2);
  short* wp2t = (short*)alloc((size_t)D * D * 2);
  short* ws2t = (short*)alloc((size_t)D * D * 2);
  short* wn2t = (short*)alloc((size_t)D * D * 2);
  short* h1   = (short*)alloc((size_t)N0C * D * 2);
  short* h2   = (short*)alloc((size_t)N1C * D * 2);
  short* l1o  = (short*)alloc((size_t)N1C * D * 2);
  short* agg1 = (short*)alloc((size_t)N1C * D * 2);
  short* agg2 = (short*)alloc((size_t)N2C * D * 2);
  // counters contiguous -> one memset clears them all
  int*   cnt0 = (int*)alloc((size_t)N1C * 4);
  int*   cur0 = (int*)alloc((size_t)N1C * 4);
  int*   cnt1 = (int*)alloc((size_t)N2C * 4);
  int*   cur1 = (int*)alloc((size_t)N2C * 4);
  size_t ctr_span = (char*)ws + off - (char*)cnt0;
  int*   off0 = (int*)alloc((size_t)(N1C + 1) * 4);
  int*   off1 = (int*)alloc((size_t)(N2C + 1) * 4);
  int*   ss0  = (int*)alloc((size_t)E0 * 4);
  float* wss0 = (float*)alloc((size_t)E0 * 4);
  int*   ss1  = (int*)alloc((size_t)E1 * 4);
  float* wss1 = (float*)alloc((size_t)E1 * 4);

  hipMemsetAsync(cnt0, 0, ctr_span, stream);

  wtrans6_k<<<dim3(D, 6), D, 0, stream>>>(Wp1, Ws1, Wn1, Wp2, Ws2, Wn2,
                                          wp1t, ws1t, wn1t, wp2t, ws2t, wn2t);

  int eb = (E0 + E1 + 255) / 256;
  hist_k<<<eb, 256, 0, stream>>>(dst0, E0, cnt0, dst1, E1, cnt1);
  scan_k<<<2, 256, 0, stream>>>(cnt0, off0, N1C, cnt1, off1, N2C);
  scat_k<<<eb, 256, 0, stream>>>(src0, dst0, w0, E0, off0, cur0, ss0, wss0,
                                 src1, dst1, w1, E1, off1, cur1, ss1, wss1);

  // h1 = relu(x @ Wp1 + bp1) -> bf16
  gemm_k<float, short, 1, 0><<<(N0C + 63) / 64, 256, 0, stream>>>(
      x, wp1t, (const short*)nullptr, nullptr, bp1, h1, N0C);
  // agg1 = segment_max(h1[src0]*w0, dst0) -> bf16
  seg_max_k<<<(N1C + 3) / 4, 256, 0, stream>>>(h1, off0, ss0, wss0, agg1, N1C);
  // l1o = relu(x[:N1] @ Ws1 + agg1 @ Wn1 + b1) -> bf16
  gemm_k<float, short, 2, 0><<<(N1C + 63) / 64, 256, 0, stream>>>(
      x, ws1t, agg1, wn1t, b1, l1o, N1C);
  // h2 = relu(l1o @ Wp2 + bp2) -> bf16
  gemm_k<short, short, 1, 0><<<(N1C + 63) / 64, 256, 0, stream>>>(
      l1o, wp2t, (const short*)nullptr, nullptr, bp2, h2, N1C);
  // agg2 = segment_max(h2[src1]*w1, dst1) -> bf16
  seg_max_k<<<(N2C + 3) / 4, 256, 0, stream>>>(h2, off1, ss1, wss1, agg2, N2C);
  // out = relu(l1o[:N2] @ Ws2 + agg2 @ Wn2 + b2) -> fp32
  gemm_k<short, short, 2, 1><<<(N2C + 63) / 64, 256, 0, stream>>>(
      l1o, ws2t, agg2, wn2t, b2, d_out, N2C);
}

// Round 4
// 334.677 us; speedup vs baseline: 5.4346x; 1.0886x over previous
//
#include <hip/hip_runtime.h>
#include <hip/hip_bf16.h>

#define D 256
#define N0C 100000
#define N1C 20000
#define N2C 4000

typedef short s16x8 __attribute__((ext_vector_type(8)));
typedef float f32x4 __attribute__((ext_vector_type(4)));

__device__ __forceinline__ short f2bf(float f) {
  __hip_bfloat16 b = __float2bfloat16(f);   // RNE hardware cvt
  union { __hip_bfloat16 h; short s; } u;
  u.h = b;
  return u.s;
}
__device__ __forceinline__ float bf2f(short s) {
  return __uint_as_float(((unsigned)(unsigned short)s) << 16);
}

// ---- x (fp32) -> xb (bf16), vectorized 8/thread
__global__ __launch_bounds__(256) void xcvt_k(const float* __restrict__ x,
                                              short* __restrict__ xb, int n8) {
  int i = blockIdx.x * 256 + threadIdx.x;
  int stride = gridDim.x * 256;
  for (; i < n8; i += stride) {
    const float4* p = (const float4*)(x + (size_t)i * 8);
    float4 f0 = p[0], f1 = p[1];
    s16x8 o;
    o[0] = f2bf(f0.x); o[1] = f2bf(f0.y); o[2] = f2bf(f0.z); o[3] = f2bf(f0.w);
    o[4] = f2bf(f1.x); o[5] = f2bf(f1.y); o[6] = f2bf(f1.z); o[7] = f2bf(f1.w);
    *(s16x8*)(xb + (size_t)i * 8) = o;
  }
}

// ---- weight transpose: 6x  W(K,N) f32 row-major -> WT(N,K) bf16 row-major
__global__ __launch_bounds__(256) void wtrans6_k(
    const float* __restrict__ W0, const float* __restrict__ W1,
    const float* __restrict__ W2, const float* __restrict__ W3,
    const float* __restrict__ W4, const float* __restrict__ W5,
    short* __restrict__ T0, short* __restrict__ T1, short* __restrict__ T2,
    short* __restrict__ T3, short* __restrict__ T4, short* __restrict__ T5)
{
  const float* Ws[6] = {W0, W1, W2, W3, W4, W5};
  short* Ts[6] = {T0, T1, T2, T3, T4, T5};
  int g = blockIdx.y, k = blockIdx.x, n = threadIdx.x;
  Ts[g][n * D + k] = f2bf(Ws[g][k * D + n]);
}

// ---- CSR build
__global__ __launch_bounds__(256) void hist_k(
    const int* __restrict__ dst0, int E0, int* __restrict__ c0,
    const int* __restrict__ dst1, int E1, int* __restrict__ c1)
{
  int i = blockIdx.x * 256 + threadIdx.x;
  if (i < E0) atomicAdd(&c0[dst0[i]], 1);
  else if (i < E0 + E1) atomicAdd(&c1[dst1[i - E0]], 1);
}

__global__ __launch_bounds__(256) void scan_k(
    const int* __restrict__ c0, int* __restrict__ o0, int n0,
    const int* __restrict__ c1, int* __restrict__ o1, int n1)
{
  const int* c = blockIdx.x ? c1 : c0;
  int* o = blockIdx.x ? o1 : o0;
  int n = blockIdx.x ? n1 : n0;
  __shared__ int lsum[256];
  int t = threadIdx.x;
  int chunk = (n + 255) / 256;
  int beg = t * chunk, end = min(beg + chunk, n);
  int s = 0;
  for (int i = beg; i < end; ++i) s += c[i];
  lsum[t] = s;
  __syncthreads();
  for (int d = 1; d < 256; d <<= 1) {
    int v = (t >= d) ? lsum[t - d] : 0;
    __syncthreads();
    lsum[t] += v;
    __syncthreads();
  }
  int run = (t == 0) ? 0 : lsum[t - 1];
  for (int i = beg; i < end; ++i) { o[i] = run; run += c[i]; }
  if (t == 255) o[n] = run;
}

// edge record = (src, w-bits) packed -> one 8B scatter / one 8B gather
__global__ __launch_bounds__(256) void scat_k(
    const int* __restrict__ src0, const int* __restrict__ dst0,
    const float* __restrict__ w0, int E0, const int* __restrict__ offs0,
    int* __restrict__ cur0, int2* __restrict__ rec0,
    const int* __restrict__ src1, const int* __restrict__ dst1,
    const float* __restrict__ w1, int E1, const int* __restrict__ offs1,
    int* __restrict__ cur1, int2* __restrict__ rec1)
{
  int i = blockIdx.x * 256 + threadIdx.x;
  if (i < E0) {
    int d = dst0[i];
    int p = offs0[d] + atomicAdd(&cur0[d], 1);
    rec0[p] = make_int2(src0[i], __float_as_int(w0[i]));
  } else if (i < E0 + E1) {
    int j = i - E0;
    int d = dst1[j];
    int p = offs1[d] + atomicAdd(&cur1[d], 1);
    rec1[p] = make_int2(src1[j], __float_as_int(w1[j]));
  }
}

// ---- per-dst gather max: one wave per dst, 64 lanes x 4 dims, 4-edge unroll
__global__ __launch_bounds__(256) void seg_max_k(
    const short* __restrict__ h, const int* __restrict__ offs,
    const int2* __restrict__ rec, short* __restrict__ agg, int ndst)
{
  int dst = blockIdx.x * 4 + (threadIdx.x >> 6);
  if (dst >= ndst) return;
  int lane = threadIdx.x & 63;
  int beg = offs[dst], end = offs[dst + 1];
  const short* hp = h + (size_t)lane * 4;
  float m[4][4];
#pragma unroll
  for (int j = 0; j < 4; j++)
#pragma unroll
    for (int d2 = 0; d2 < 4; d2++) m[j][d2] = 0.f;
  int i = beg;
  for (; i + 3 < end; i += 4) {
    int2 r0 = rec[i], r1 = rec[i + 1], r2 = rec[i + 2], r3 = rec[i + 3];
    short4 h0 = *(const short4*)(hp + (size_t)r0.x * D);
    short4 h1 = *(const short4*)(hp + (size_t)r1.x * D);
    short4 h2 = *(const short4*)(hp + (size_t)r2.x * D);
    short4 h3 = *(const short4*)(hp + (size_t)r3.x * D);
    float w0 = __int_as_float(r0.y), w1 = __int_as_float(r1.y);
    float w2 = __int_as_float(r2.y), w3 = __int_as_float(r3.y);
    m[0][0] = fmaxf(m[0][0], bf2f(h0.x) * w0); m[0][1] = fmaxf(m[0][1], bf2f(h0.y) * w0);
    m[0][2] = fmaxf(m[0][2], bf2f(h0.z) * w0); m[0][3] = fmaxf(m[0][3], bf2f(h0.w) * w0);
    m[1][0] = fmaxf(m[1][0], bf2f(h1.x) * w1); m[1][1] = fmaxf(m[1][1], bf2f(h1.y) * w1);
    m[1][2] = fmaxf(m[1][2], bf2f(h1.z) * w1); m[1][3] = fmaxf(m[1][3], bf2f(h1.w) * w1);
    m[2][0] = fmaxf(m[2][0], bf2f(h2.x) * w2); m[2][1] = fmaxf(m[2][1], bf2f(h2.y) * w2);
    m[2][2] = fmaxf(m[2][2], bf2f(h2.z) * w2); m[2][3] = fmaxf(m[2][3], bf2f(h2.w) * w2);
    m[3][0] = fmaxf(m[3][0], bf2f(h3.x) * w3); m[3][1] = fmaxf(m[3][1], bf2f(h3.y) * w3);
    m[3][2] = fmaxf(m[3][2], bf2f(h3.z) * w3); m[3][3] = fmaxf(m[3][3], bf2f(h3.w) * w3);
  }
  for (; i < end; ++i) {
    int2 r0 = rec[i];
    short4 h0 = *(const short4*)(hp + (size_t)r0.x * D);
    float w0 = __int_as_float(r0.y);
    m[0][0] = fmaxf(m[0][0], bf2f(h0.x) * w0); m[0][1] = fmaxf(m[0][1], bf2f(h0.y) * w0);
    m[0][2] = fmaxf(m[0][2], bf2f(h0.z) * w0); m[0][3] = fmaxf(m[0][3], bf2f(h0.w) * w0);
  }
  short4 o;
  o.x = f2bf(fmaxf(fmaxf(m[0][0], m[1][0]), fmaxf(m[2][0], m[3][0])));
  o.y = f2bf(fmaxf(fmaxf(m[0][1], m[1][1]), fmaxf(m[2][1], m[3][1])));
  o.z = f2bf(fmaxf(fmaxf(m[0][2], m[1][2]), fmaxf(m[2][2], m[3][2])));
  o.w = f2bf(fmaxf(fmaxf(m[0][3], m[1][3]), fmaxf(m[2][3], m[3][3])));
  *(short4*)(agg + (size_t)dst * D + lane * 4) = o;
}

// ---- A-stationary GEMM: out = relu( A1 @ B1T^T [+ A2 @ B2T^T] + bias )
// All A bf16. Wave = 32 rows x 64 cols; A strip register-resident (16 s16x8,
// loaded in prologue -> off critical path). B streamed, 3-buffer depth-2
// prefetch (B is 128KB, L1/L2-hot everywhere). Block = 4 waves stacked in M
// (128 rows); grid = (ceil(M/128), 4 col-groups) -> A read exactly once.
template<int NSRC, int F32OUT>
__global__ __launch_bounds__(256, 3) void gemm_k(
    const short* __restrict__ A1, const short* __restrict__ B1T,
    const short* __restrict__ A2, const short* __restrict__ B2T,
    const float* __restrict__ bias, void* __restrict__ outp, int M)
{
  int wave = threadIdx.x >> 6, lane = threadIdx.x & 63;
  int lr = lane & 15;
  int kg = lane >> 4;
  int m_base = blockIdx.x * 128 + wave * 32;
  int n_base = blockIdx.y * 64;

  f32x4 acc[2][4];
#pragma unroll
  for (int t = 0; t < 2; t++)
#pragma unroll
    for (int u = 0; u < 4; u++) acc[t][u] = (f32x4)(0.0f);

  const short* As[2] = {A1, A2};
  const short* Bs[2] = {B1T, B2T};

  int row[2];
#pragma unroll
  for (int t = 0; t < 2; t++) {
    int r = m_base + t * 16 + lr;
    row[t] = r < M ? r : M - 1;
  }

  for (int s = 0; s < NSRC; ++s) {
    const short* A = As[s];
    const short* BT = Bs[s] + (size_t)n_base * D;
    // prologue: wave's whole A strip -> registers (16 independent 16B loads)
    s16x8 areg[2][8];
#pragma unroll
    for (int t = 0; t < 2; t++)
#pragma unroll
      for (int kc = 0; kc < 8; kc++)
        areg[t][kc] = *(const s16x8*)(A + (size_t)row[t] * D + kc * 32 + kg * 8);
    // B stream, rotating 3-buffer, prefetch depth 2
    s16x8 b[3][4];
#pragma unroll
    for (int u = 0; u < 4; u++) {
      b[0][u] = *(const s16x8*)(BT + (size_t)(u * 16 + lr) * D + 0 * 32 + kg * 8);
      b[1][u] = *(const s16x8*)(BT + (size_t)(u * 16 + lr) * D + 1 * 32 + kg * 8);
    }
#pragma unroll
    for (int kc = 0; kc < 8; kc++) {
      if (kc + 2 < 8) {
#pragma unroll
        for (int u = 0; u < 4; u++)
          b[(kc + 2) % 3][u] =
              *(const s16x8*)(BT + (size_t)(u * 16 + lr) * D + (kc + 2) * 32 + kg * 8);
      }
#pragma unroll
      for (int t = 0; t < 2; t++)
#pragma unroll
        for (int u = 0; u < 4; u++)
          acc[t][u] = __builtin_amdgcn_mfma_f32_16x16x32_bf16(
              areg[t][kc], b[kc % 3][u], acc[t][u], 0, 0, 0);
    }
  }

  if (m_base < M) {  // all M are multiples of 32 -> whole wave in or out
#pragma unroll
    for (int t = 0; t < 2; t++)
#pragma unroll
      for (int u = 0; u < 4; u++) {
        int c = n_base + u * 16 + lr;
        float bv = bias[c];
        int rbase = m_base + t * 16 + kg * 4;
#pragma unroll
        for (int i = 0; i < 4; i++) {
          float v = acc[t][u][i] + bv;
          v = v > 0.0f ? v : 0.0f;
          size_t idx = (size_t)(rbase + i) * D + c;
          if (F32OUT) ((float*)outp)[idx] = v;
          else        ((short*)outp)[idx] = f2bf(v);
        }
      }
  }
}

extern "C" void kernel_launch(void* const* d_in, const int* in_sizes, int n_in,
                              void* d_out, int out_size, void* d_ws, size_t ws_size,
                              hipStream_t stream)
{
  const float* x    = (const float*)d_in[0];
  const int*   src0 = (const int*)d_in[1];
  const int*   dst0 = (const int*)d_in[2];
  const float* w0   = (const float*)d_in[3];
  const int*   src1 = (const int*)d_in[4];
  const int*   dst1 = (const int*)d_in[5];
  const float* w1   = (const float*)d_in[6];
  const float* Wp1  = (const float*)d_in[7];
  const float* bp1  = (const float*)d_in[8];
  const float* Ws1  = (const float*)d_in[9];
  const float* Wn1  = (const float*)d_in[10];
  const float* b1   = (const float*)d_in[11];
  const float* Wp2  = (const float*)d_in[12];
  const float* bp2  = (const float*)d_in[13];
  const float* Ws2  = (const float*)d_in[14];
  const float* Wn2  = (const float*)d_in[15];
  const float* b2   = (const float*)d_in[16];

  const int E0 = in_sizes[1], E1 = in_sizes[4];

  char* ws = (char*)d_ws;
  size_t off = 0;
  auto alloc = [&](size_t bytes) {
    void* p = ws + off;
    off += (bytes + 255) & ~(size_t)255;
    return p;
  };
  short* wp1t = (short*)alloc((size_t)D * D * 2);
  short* ws1t = (short*)alloc((size_t)D * D * 2);
  short* wn1t = (short*)alloc((size_t)D * D * 2);
  short* wp2t = (short*)alloc((size_t)D * D * 2);
  short* ws2t = (short*)alloc((size_t)D * D * 2);
  short* wn2t = (short*)alloc((size_t)D * D * 2);
  short* xb   = (short*)alloc((size_t)N0C * D * 2);
  short* h1   = (short*)alloc((size_t)N0C * D * 2);
  short* h2   = (short*)alloc((size_t)N1C * D * 2);
  short* l1o  = (short*)alloc((size_t)N1C * D * 2);
  short* agg1 = (short*)alloc((size_t)N1C * D * 2);
  short* agg2 = (short*)alloc((size_t)N2C * D * 2);
  int*   cnt0 = (int*)alloc((size_t)N1C * 4);
  int*   cur0 = (int*)alloc((size_t)N1C * 4);
  int*   cnt1 = (int*)alloc((size_t)N2C * 4);
  int*   cur1 = (int*)alloc((size_t)N2C * 4);
  size_t ctr_span = (char*)ws + off - (char*)cnt0;
  int*   off0 = (int*)alloc((size_t)(N1C + 1) * 4);
  int*   off1 = (int*)alloc((size_t)(N2C + 1) * 4);
  int2*  rec0 = (int2*)alloc((size_t)E0 * 8);
  int2*  rec1 = (int2*)alloc((size_t)E1 * 8);

  hipMemsetAsync(cnt0, 0, ctr_span, stream);

  xcvt_k<<<2048, 256, 0, stream>>>(x, xb, N0C * D / 8);
  wtrans6_k<<<dim3(D, 6), D, 0, stream>>>(Wp1, Ws1, Wn1, Wp2, Ws2, Wn2,
                                          wp1t, ws1t, wn1t, wp2t, ws2t, wn2t);

  int eb = (E0 + E1 + 255) / 256;
  hist_k<<<eb, 256, 0, stream>>>(dst0, E0, cnt0, dst1, E1, cnt1);
  scan_k<<<2, 256, 0, stream>>>(cnt0, off0, N1C, cnt1, off1, N2C);
  scat_k<<<eb, 256, 0, stream>>>(src0, dst0, w0, E0, off0, cur0, rec0,
                                 src1, dst1, w1, E1, off1, cur1, rec1);

  // h1 = relu(xb @ Wp1 + bp1) -> bf16
  gemm_k<1, 0><<<dim3((N0C + 127) / 128, 4), 256, 0, stream>>>(
      xb, wp1t, (const short*)nullptr, nullptr, bp1, h1, N0C);
  // agg1 = segment_max(h1[src0]*w0, dst0) -> bf16
  seg_max_k<<<(N1C + 3) / 4, 256, 0, stream>>>(h1, off0, rec0, agg1, N1C);
  // l1o = relu(xb[:N1] @ Ws1 + agg1 @ Wn1 + b1) -> bf16
  gemm_k<2, 0><<<dim3((N1C + 127) / 128, 4), 256, 0, stream>>>(
      xb, ws1t, agg1, wn1t, b1, l1o, N1C);
  // h2 = relu(l1o @ Wp2 + bp2) -> bf16
  gemm_k<1, 0><<<dim3((N1C + 127) / 128, 4), 256, 0, stream>>>(
      l1o, wp2t, (const short*)nullptr, nullptr, bp2, h2, N1C);
  // agg2 = segment_max(h2[src1]*w1, dst1) -> bf16
  seg_max_k<<<(N2C + 3) / 4, 256, 0, stream>>>(h2, off1, rec1, agg2, N2C);
  // out = relu(l1o[:N2] @ Ws2 + agg2 @ Wn2 + b2) -> fp32
  gemm_k<2, 1><<<dim3((N2C + 127) / 128, 4), 256, 0, stream>>>(
      l1o, ws2t, agg2, wn2t, b2, d_out, N2C);
}

// Round 5
// 243.514 us; speedup vs baseline: 7.4692x; 1.3744x over previous
//
#include <hip/hip_runtime.h>
#include <hip/hip_bf16.h>

#define D 256
#define N0C 100000
#define N1C 20000
#define N2C 4000

typedef short s16x8 __attribute__((ext_vector_type(8)));
typedef float f32x4 __attribute__((ext_vector_type(4)));

typedef __attribute__((address_space(3))) void lds_v;
typedef __attribute__((address_space(1))) void glb_v;

__device__ __forceinline__ short f2bf(float f) {
  __hip_bfloat16 b = __float2bfloat16(f);   // RNE hardware cvt
  union { __hip_bfloat16 h; short s; } u;
  u.h = b;
  return u.s;
}
__device__ __forceinline__ float bf2f(short s) {
  return __uint_as_float(((unsigned)(unsigned short)s) << 16);
}

// ---- x (fp32) -> xb (bf16), vectorized 8/thread
__global__ __launch_bounds__(256) void xcvt_k(const float* __restrict__ x,
                                              short* __restrict__ xb, int n8) {
  int i = blockIdx.x * 256 + threadIdx.x;
  int stride = gridDim.x * 256;
  for (; i < n8; i += stride) {
    const float4* p = (const float4*)(x + (size_t)i * 8);
    float4 f0 = p[0], f1 = p[1];
    s16x8 o;
    o[0] = f2bf(f0.x); o[1] = f2bf(f0.y); o[2] = f2bf(f0.z); o[3] = f2bf(f0.w);
    o[4] = f2bf(f1.x); o[5] = f2bf(f1.y); o[6] = f2bf(f1.z); o[7] = f2bf(f1.w);
    *(s16x8*)(xb + (size_t)i * 8) = o;
  }
}

// ---- weight -> fragment-major packed bf16.
// chunk c (0..8191): lane=c&63, kc=(c>>6)&7, g16=c>>9.
// chunk holds B-frag for MFMA 16x16x32: col=g16*16+(lane&15), k=kc*32+(lane>>4)*8+j
__global__ __launch_bounds__(256) void wtransp_k(
    const float* __restrict__ W0, const float* __restrict__ W1,
    const float* __restrict__ W2, const float* __restrict__ W3,
    const float* __restrict__ W4, const float* __restrict__ W5,
    short* __restrict__ T0, short* __restrict__ T1, short* __restrict__ T2,
    short* __restrict__ T3, short* __restrict__ T4, short* __restrict__ T5)
{
  const float* Ws[6] = {W0, W1, W2, W3, W4, W5};
  short* Ts[6] = {T0, T1, T2, T3, T4, T5};
  int g = blockIdx.y;
  int c = blockIdx.x * 256 + threadIdx.x;  // 0..8191
  int lane = c & 63, kc = (c >> 6) & 7, g16 = c >> 9;
  int col = g16 * 16 + (lane & 15);
  int kbase = kc * 32 + (lane >> 4) * 8;
  const float* W = Ws[g];
  s16x8 o;
#pragma unroll
  for (int j = 0; j < 8; ++j) o[j] = f2bf(W[(size_t)(kbase + j) * D + col]);
  *(s16x8*)(Ts[g] + (size_t)c * 8) = o;
}

// ---- CSR build
__global__ __launch_bounds__(256) void hist_k(
    const int* __restrict__ dst0, int E0, int* __restrict__ c0,
    const int* __restrict__ dst1, int E1, int* __restrict__ c1)
{
  int i = blockIdx.x * 256 + threadIdx.x;
  if (i < E0) atomicAdd(&c0[dst0[i]], 1);
  else if (i < E0 + E1) atomicAdd(&c1[dst1[i - E0]], 1);
}

__global__ __launch_bounds__(256) void scan_k(
    const int* __restrict__ c0, int* __restrict__ o0, int n0,
    const int* __restrict__ c1, int* __restrict__ o1, int n1)
{
  const int* c = blockIdx.x ? c1 : c0;
  int* o = blockIdx.x ? o1 : o0;
  int n = blockIdx.x ? n1 : n0;
  __shared__ int lsum[256];
  int t = threadIdx.x;
  int chunk = (n + 255) / 256;
  int beg = t * chunk, end = min(beg + chunk, n);
  int s = 0;
  for (int i = beg; i < end; ++i) s += c[i];
  lsum[t] = s;
  __syncthreads();
  for (int d = 1; d < 256; d <<= 1) {
    int v = (t >= d) ? lsum[t - d] : 0;
    __syncthreads();
    lsum[t] += v;
    __syncthreads();
  }
  int run = (t == 0) ? 0 : lsum[t - 1];
  for (int i = beg; i < end; ++i) { o[i] = run; run += c[i]; }
  if (t == 255) o[n] = run;
}

__global__ __launch_bounds__(256) void scat_k(
    const int* __restrict__ src0, const int* __restrict__ dst0,
    const float* __restrict__ w0, int E0, const int* __restrict__ offs0,
    int* __restrict__ cur0, int2* __restrict__ rec0,
    const int* __restrict__ src1, const int* __restrict__ dst1,
    const float* __restrict__ w1, int E1, const int* __restrict__ offs1,
    int* __restrict__ cur1, int2* __restrict__ rec1)
{
  int i = blockIdx.x * 256 + threadIdx.x;
  if (i < E0) {
    int d = dst0[i];
    int p = offs0[d] + atomicAdd(&cur0[d], 1);
    rec0[p] = make_int2(src0[i], __float_as_int(w0[i]));
  } else if (i < E0 + E1) {
    int j = i - E0;
    int d = dst1[j];
    int p = offs1[d] + atomicAdd(&cur1[d], 1);
    rec1[p] = make_int2(src1[j], __float_as_int(w1[j]));
  }
}

// ---- per-dst gather max: one wave per dst, 64 lanes x 4 dims, 4-edge unroll
__global__ __launch_bounds__(256) void seg_max_k(
    const short* __restrict__ h, const int* __restrict__ offs,
    const int2* __restrict__ rec, short* __restrict__ agg, int ndst)
{
  int dst = blockIdx.x * 4 + (threadIdx.x >> 6);
  if (dst >= ndst) return;
  int lane = threadIdx.x & 63;
  int beg = offs[dst], end = offs[dst + 1];
  const short* hp = h + (size_t)lane * 4;
  float m[4][4];
#pragma unroll
  for (int j = 0; j < 4; j++)
#pragma unroll
    for (int d2 = 0; d2 < 4; d2++) m[j][d2] = 0.f;
  int i = beg;
  for (; i + 3 < end; i += 4) {
    int2 r0 = rec[i], r1 = rec[i + 1], r2 = rec[i + 2], r3 = rec[i + 3];
    short4 h0 = *(const short4*)(hp + (size_t)r0.x * D);
    short4 h1 = *(const short4*)(hp + (size_t)r1.x * D);
    short4 h2 = *(const short4*)(hp + (size_t)r2.x * D);
    short4 h3 = *(const short4*)(hp + (size_t)r3.x * D);
    float w0 = __int_as_float(r0.y), w1 = __int_as_float(r1.y);
    float w2 = __int_as_float(r2.y), w3 = __int_as_float(r3.y);
    m[0][0] = fmaxf(m[0][0], bf2f(h0.x) * w0); m[0][1] = fmaxf(m[0][1], bf2f(h0.y) * w0);
    m[0][2] = fmaxf(m[0][2], bf2f(h0.z) * w0); m[0][3] = fmaxf(m[0][3], bf2f(h0.w) * w0);
    m[1][0] = fmaxf(m[1][0], bf2f(h1.x) * w1); m[1][1] = fmaxf(m[1][1], bf2f(h1.y) * w1);
    m[1][2] = fmaxf(m[1][2], bf2f(h1.z) * w1); m[1][3] = fmaxf(m[1][3], bf2f(h1.w) * w1);
    m[2][0] = fmaxf(m[2][0], bf2f(h2.x) * w2); m[2][1] = fmaxf(m[2][1], bf2f(h2.y) * w2);
    m[2][2] = fmaxf(m[2][2], bf2f(h2.z) * w2); m[2][3] = fmaxf(m[2][3], bf2f(h2.w) * w2);
    m[3][0] = fmaxf(m[3][0], bf2f(h3.x) * w3); m[3][1] = fmaxf(m[3][1], bf2f(h3.y) * w3);
    m[3][2] = fmaxf(m[3][2], bf2f(h3.z) * w3); m[3][3] = fmaxf(m[3][3], bf2f(h3.w) * w3);
  }
  for (; i < end; ++i) {
    int2 r0 = rec[i];
    short4 h0 = *(const short4*)(hp + (size_t)r0.x * D);
    float w0 = __int_as_float(r0.y);
    m[0][0] = fmaxf(m[0][0], bf2f(h0.x) * w0); m[0][1] = fmaxf(m[0][1], bf2f(h0.y) * w0);
    m[0][2] = fmaxf(m[0][2], bf2f(h0.z) * w0); m[0][3] = fmaxf(m[0][3], bf2f(h0.w) * w0);
  }
  short4 o;
  o.x = f2bf(fmaxf(fmaxf(m[0][0], m[1][0]), fmaxf(m[2][0], m[3][0])));
  o.y = f2bf(fmaxf(fmaxf(m[0][1], m[1][1]), fmaxf(m[2][1], m[3][1])));
  o.z = f2bf(fmaxf(fmaxf(m[0][2], m[1][2]), fmaxf(m[2][2], m[3][2])));
  o.w = f2bf(fmaxf(fmaxf(m[0][3], m[1][3]), fmaxf(m[2][3], m[3][3])));
  *(short4*)(agg + (size_t)dst * D + lane * 4) = o;
}

// ---- GEMM: out = relu( A1 @ W1 [+ A2 @ W2] + bias )
// Block = 64 rows x 256 cols, 4 waves (wave w -> cols w*64..w*64+63).
// A (bf16, row-major) staged to LDS via global_load_lds (linear dest,
// inverse-XOR-swizzled source so ds_read_b128 is bank-conflict-free).
// B pre-packed fragment-major -> each wave's 64-col panel = 32 coalesced
// 16B loads, fully register-resident (128 VGPR). Counted vmcnt(32) wait:
// stage DMAs are FIFO-oldest, B loads stay in flight across the barrier.
template<int NSRC, int F32OUT>
__global__ __launch_bounds__(256, 2) void gemm_k(
    const short* __restrict__ A1, const short* __restrict__ B1p,
    const short* __restrict__ A2, const short* __restrict__ B2p,
    const float* __restrict__ bias, void* __restrict__ outp, int M)
{
  __shared__ short smem[NSRC * 64 * 256];
  const int tid = threadIdx.x;
  const int wave = tid >> 6, lane = tid & 63;
  const int lr = lane & 15, kg = lane >> 4;
  const int m_base = blockIdx.x * 64;

  const short* As[2] = {A1, A2};
  const short* Bs[2] = {B1p, B2p};

  // ---- stage A tile(s): 32KB contiguous copy per source
#pragma unroll
  for (int s = 0; s < NSRC; ++s) {
#pragma unroll
    for (int it = 0; it < 8; ++it) {
      int L = it * 4096 + tid * 16;            // byte offset in tile
      int row = L >> 9;
      int colb = (L & 511) ^ ((row & 7) << 4); // inverse swizzle on source
      int grow = m_base + row;
      grow = grow < M ? grow : M - 1;
      const char* gp = (const char*)As[s] + (size_t)grow * 512 + colb;
      char* lp = (char*)smem + s * 32768 + L;  // linear LDS dest
      __builtin_amdgcn_global_load_lds((const glb_v*)gp, (lds_v*)lp, 16, 0, 0);
    }
  }
  __builtin_amdgcn_sched_barrier(0);  // keep B loads after the DMA issues

  f32x4 acc[4][4];
#pragma unroll
  for (int t = 0; t < 4; t++)
#pragma unroll
    for (int u = 0; u < 4; u++) acc[t][u] = (f32x4)(0.0f);

#pragma unroll
  for (int s = 0; s < NSRC; ++s) {
    // B panel resident: 32 coalesced 16B loads (1KB/wave-instr)
    s16x8 breg[4][8];
#pragma unroll
    for (int u = 0; u < 4; ++u)
#pragma unroll
      for (int kc = 0; kc < 8; ++kc) {
        int g16 = wave * 4 + u;
        breg[u][kc] = *(const s16x8*)(Bs[s] + ((size_t)((g16 * 8 + kc) * 64 + lane)) * 8);
      }
    if (s == 0) {
      // stage DMAs (8*NSRC, oldest) done when <=32 outstanding remain
      asm volatile("s_waitcnt vmcnt(32)" ::: "memory");
      __builtin_amdgcn_s_barrier();
      __builtin_amdgcn_sched_barrier(0);
    }
#pragma unroll
    for (int kc = 0; kc < 8; ++kc) {
      s16x8 a[4];
#pragma unroll
      for (int t = 0; t < 4; ++t) {
        int row = t * 16 + lr;
        int base = (row << 9) + kc * 64 + kg * 16;
        int off = s * 32768 + (base ^ ((row & 7) << 4));
        a[t] = *(const s16x8*)((const char*)smem + off);
      }
#pragma unroll
      for (int t = 0; t < 4; ++t)
#pragma unroll
        for (int u = 0; u < 4; ++u)
          acc[t][u] = __builtin_amdgcn_mfma_f32_16x16x32_bf16(a[t], breg[u][kc], acc[t][u], 0, 0, 0);
    }
  }

  // ---- epilogue: D layout col=lane&15, row=(lane>>4)*4+i
#pragma unroll
  for (int t = 0; t < 4; ++t) {
    int grow0 = m_base + t * 16 + kg * 4;
    if (m_base + t * 16 < M) {
#pragma unroll
      for (int u = 0; u < 4; ++u) {
        int col = wave * 64 + u * 16 + lr;
        float bv = bias[col];
#pragma unroll
        for (int i = 0; i < 4; ++i) {
          float v = acc[t][u][i] + bv;
          v = v > 0.0f ? v : 0.0f;
          size_t idx = (size_t)(grow0 + i) * D + col;
          if (F32OUT) ((float*)outp)[idx] = v;
          else        ((short*)outp)[idx] = f2bf(v);
        }
      }
    }
  }
}

extern "C" void kernel_launch(void* const* d_in, const int* in_sizes, int n_in,
                              void* d_out, int out_size, void* d_ws, size_t ws_size,
                              hipStream_t stream)
{
  const float* x    = (const float*)d_in[0];
  const int*   src0 = (const int*)d_in[1];
  const int*   dst0 = (const int*)d_in[2];
  const float* w0   = (const float*)d_in[3];
  const int*   src1 = (const int*)d_in[4];
  const int*   dst1 = (const int*)d_in[5];
  const float* w1   = (const float*)d_in[6];
  const float* Wp1  = (const float*)d_in[7];
  const float* bp1  = (const float*)d_in[8];
  const float* Ws1  = (const float*)d_in[9];
  const float* Wn1  = (const float*)d_in[10];
  const float* b1   = (const float*)d_in[11];
  const float* Wp2  = (const float*)d_in[12];
  const float* bp2  = (const float*)d_in[13];
  const float* Ws2  = (const float*)d_in[14];
  const float* Wn2  = (const float*)d_in[15];
  const float* b2   = (const float*)d_in[16];

  const int E0 = in_sizes[1], E1 = in_sizes[4];

  char* ws = (char*)d_ws;
  size_t off = 0;
  auto alloc = [&](size_t bytes) {
    void* p = ws + off;
    off += (bytes + 255) & ~(size_t)255;
    return p;
  };
  short* wp1t = (short*)alloc((size_t)D * D * 2);
  short* ws1t = (short*)alloc((size_t)D * D * 2);
  short* wn1t = (short*)alloc((size_t)D * D * 2);
  short* wp2t = (short*)alloc((size_t)D * D * 2);
  short* ws2t = (short*)alloc((size_t)D * D * 2);
  short* wn2t = (short*)alloc((size_t)D * D * 2);
  short* xb   = (short*)alloc((size_t)N0C * D * 2);
  short* h1   = (short*)alloc((size_t)N0C * D * 2);
  short* h2   = (short*)alloc((size_t)N1C * D * 2);
  short* l1o  = (short*)alloc((size_t)N1C * D * 2);
  short* agg1 = (short*)alloc((size_t)N1C * D * 2);
  short* agg2 = (short*)alloc((size_t)N2C * D * 2);
  int*   cnt0 = (int*)alloc((size_t)N1C * 4);
  int*   cur0 = (int*)alloc((size_t)N1C * 4);
  int*   cnt1 = (int*)alloc((size_t)N2C * 4);
  int*   cur1 = (int*)alloc((size_t)N2C * 4);
  size_t ctr_span = (char*)ws + off - (char*)cnt0;
  int*   off0 = (int*)alloc((size_t)(N1C + 1) * 4);
  int*   off1 = (int*)alloc((size_t)(N2C + 1) * 4);
  int2*  rec0 = (int2*)alloc((size_t)E0 * 8);
  int2*  rec1 = (int2*)alloc((size_t)E1 * 8);

  hipMemsetAsync(cnt0, 0, ctr_span, stream);

  xcvt_k<<<2048, 256, 0, stream>>>(x, xb, N0C * D / 8);
  wtransp_k<<<dim3(32, 6), 256, 0, stream>>>(Wp1, Ws1, Wn1, Wp2, Ws2, Wn2,
                                             wp1t, ws1t, wn1t, wp2t, ws2t, wn2t);

  int eb = (E0 + E1 + 255) / 256;
  hist_k<<<eb, 256, 0, stream>>>(dst0, E0, cnt0, dst1, E1, cnt1);
  scan_k<<<2, 256, 0, stream>>>(cnt0, off0, N1C, cnt1, off1, N2C);
  scat_k<<<eb, 256, 0, stream>>>(src0, dst0, w0, E0, off0, cur0, rec0,
                                 src1, dst1, w1, E1, off1, cur1, rec1);

  // h1 = relu(xb @ Wp1 + bp1) -> bf16
  gemm_k<1, 0><<<(N0C + 63) / 64, 256, 0, stream>>>(
      xb, wp1t, (const short*)nullptr, nullptr, bp1, h1, N0C);
  // agg1 = segment_max(h1[src0]*w0, dst0) -> bf16
  seg_max_k<<<(N1C + 3) / 4, 256, 0, stream>>>(h1, off0, rec0, agg1, N1C);
  // l1o = relu(xb[:N1] @ Ws1 + agg1 @ Wn1 + b1) -> bf16
  gemm_k<2, 0><<<(N1C + 63) / 64, 256, 0, stream>>>(
      xb, ws1t, agg1, wn1t, b1, l1o, N1C);
  // h2 = relu(l1o @ Wp2 + bp2) -> bf16
  gemm_k<1, 0><<<(N1C + 63) / 64, 256, 0, stream>>>(
      l1o, wp2t, (const short*)nullptr, nullptr, bp2, h2, N1C);
  // agg2 = segment_max(h2[src1]*w1, dst1) -> bf16
  seg_max_k<<<(N2C + 3) / 4, 256, 0, stream>>>(h2, off1, rec1, agg2, N2C);
  // out = relu(l1o[:N2] @ Ws2 + agg2 @ Wn2 + b2) -> fp32
  gemm_k<2, 1><<<(N2C + 63) / 64, 256, 0, stream>>>(
      l1o, ws2t, agg2, wn2t, b2, d_out, N2C);
}

// Round 6
// 233.198 us; speedup vs baseline: 7.7996x; 1.0442x over previous
//
#include <hip/hip_runtime.h>
#include <hip/hip_bf16.h>

#define D 256
#define N0C 100000
#define N1C 20000
#define N2C 4000

typedef short s16x8 __attribute__((ext_vector_type(8)));
typedef float f32x4 __attribute__((ext_vector_type(4)));

typedef __attribute__((address_space(3))) void lds_v;
typedef __attribute__((address_space(1))) void glb_v;

template<class A, class B> struct same_t { static constexpr bool v = false; };
template<class A> struct same_t<A, A> { static constexpr bool v = true; };

__device__ __forceinline__ short f2bf(float f) {
  __hip_bfloat16 b = __float2bfloat16(f);   // RNE hardware cvt
  union { __hip_bfloat16 h; short s; } u;
  u.h = b;
  return u.s;
}
__device__ __forceinline__ float bf2f(short s) {
  return __uint_as_float(((unsigned)(unsigned short)s) << 16);
}

// ---- weight -> fragment-major packed bf16 (+ zero the CSR counters).
// chunk c (0..8191): lane=c&63, kc=(c>>6)&7, g16=c>>9.
// chunk holds B-frag for MFMA 16x16x32: col=g16*16+(lane&15), k=kc*32+(lane>>4)*8+j
__global__ __launch_bounds__(256) void wtransp_k(
    const float* __restrict__ W0, const float* __restrict__ W1,
    const float* __restrict__ W2, const float* __restrict__ W3,
    const float* __restrict__ W4, const float* __restrict__ W5,
    short* __restrict__ T0, short* __restrict__ T1, short* __restrict__ T2,
    short* __restrict__ T3, short* __restrict__ T4, short* __restrict__ T5,
    int* __restrict__ ctrs, int nctr)
{
  int flat = (blockIdx.y * gridDim.x + blockIdx.x) * 256 + threadIdx.x;
  if (flat < nctr) ctrs[flat] = 0;

  const float* Ws[6] = {W0, W1, W2, W3, W4, W5};
  short* Ts[6] = {T0, T1, T2, T3, T4, T5};
  int g = blockIdx.y;
  int c = blockIdx.x * 256 + threadIdx.x;  // 0..8191
  int lane = c & 63, kc = (c >> 6) & 7, g16 = c >> 9;
  int col = g16 * 16 + (lane & 15);
  int kbase = kc * 32 + (lane >> 4) * 8;
  const float* W = Ws[g];
  s16x8 o;
#pragma unroll
  for (int j = 0; j < 8; ++j) o[j] = f2bf(W[(size_t)(kbase + j) * D + col]);
  *(s16x8*)(Ts[g] + (size_t)c * 8) = o;
}

// ---- CSR build
__global__ __launch_bounds__(256) void hist_k(
    const int* __restrict__ dst0, int E0, int* __restrict__ c0,
    const int* __restrict__ dst1, int E1, int* __restrict__ c1)
{
  int i = blockIdx.x * 256 + threadIdx.x;
  if (i < E0) atomicAdd(&c0[dst0[i]], 1);
  else if (i < E0 + E1) atomicAdd(&c1[dst1[i - E0]], 1);
}

__global__ __launch_bounds__(256) void scan_k(
    const int* __restrict__ c0, int* __restrict__ o0, int n0,
    const int* __restrict__ c1, int* __restrict__ o1, int n1)
{
  const int* c = blockIdx.x ? c1 : c0;
  int* o = blockIdx.x ? o1 : o0;
  int n = blockIdx.x ? n1 : n0;
  __shared__ int lsum[256];
  int t = threadIdx.x;
  int chunk = (n + 255) / 256;
  int beg = t * chunk, end = min(beg + chunk, n);
  int s = 0;
  for (int i = beg; i < end; ++i) s += c[i];
  lsum[t] = s;
  __syncthreads();
  for (int d = 1; d < 256; d <<= 1) {
    int v = (t >= d) ? lsum[t - d] : 0;
    __syncthreads();
    lsum[t] += v;
    __syncthreads();
  }
  int run = (t == 0) ? 0 : lsum[t - 1];
  for (int i = beg; i < end; ++i) { o[i] = run; run += c[i]; }
  if (t == 255) o[n] = run;
}

__global__ __launch_bounds__(256) void scat_k(
    const int* __restrict__ src0, const int* __restrict__ dst0,
    const float* __restrict__ w0, int E0, const int* __restrict__ offs0,
    int* __restrict__ cur0, int2* __restrict__ rec0,
    const int* __restrict__ src1, const int* __restrict__ dst1,
    const float* __restrict__ w1, int E1, const int* __restrict__ offs1,
    int* __restrict__ cur1, int2* __restrict__ rec1)
{
  int i = blockIdx.x * 256 + threadIdx.x;
  if (i < E0) {
    int d = dst0[i];
    int p = offs0[d] + atomicAdd(&cur0[d], 1);
    rec0[p] = make_int2(src0[i], __float_as_int(w0[i]));
  } else if (i < E0 + E1) {
    int j = i - E0;
    int d = dst1[j];
    int p = offs1[d] + atomicAdd(&cur1[d], 1);
    rec1[p] = make_int2(src1[j], __float_as_int(w1[j]));
  }
}

// ---- per-dst gather max: one wave per dst, 64 lanes x 4 dims, 4-edge unroll
__global__ __launch_bounds__(256) void seg_max_k(
    const short* __restrict__ h, const int* __restrict__ offs,
    const int2* __restrict__ rec, short* __restrict__ agg, int ndst)
{
  int dst = blockIdx.x * 4 + (threadIdx.x >> 6);
  if (dst >= ndst) return;
  int lane = threadIdx.x & 63;
  int beg = offs[dst], end = offs[dst + 1];
  const short* hp = h + (size_t)lane * 4;
  float m[4][4];
#pragma unroll
  for (int j = 0; j < 4; j++)
#pragma unroll
    for (int d2 = 0; d2 < 4; d2++) m[j][d2] = 0.f;
  int i = beg;
  for (; i + 3 < end; i += 4) {
    int2 r0 = rec[i], r1 = rec[i + 1], r2 = rec[i + 2], r3 = rec[i + 3];
    short4 h0 = *(const short4*)(hp + (size_t)r0.x * D);
    short4 h1 = *(const short4*)(hp + (size_t)r1.x * D);
    short4 h2 = *(const short4*)(hp + (size_t)r2.x * D);
    short4 h3 = *(const short4*)(hp + (size_t)r3.x * D);
    float w0 = __int_as_float(r0.y), w1 = __int_as_float(r1.y);
    float w2 = __int_as_float(r2.y), w3 = __int_as_float(r3.y);
    m[0][0] = fmaxf(m[0][0], bf2f(h0.x) * w0); m[0][1] = fmaxf(m[0][1], bf2f(h0.y) * w0);
    m[0][2] = fmaxf(m[0][2], bf2f(h0.z) * w0); m[0][3] = fmaxf(m[0][3], bf2f(h0.w) * w0);
    m[1][0] = fmaxf(m[1][0], bf2f(h1.x) * w1); m[1][1] = fmaxf(m[1][1], bf2f(h1.y) * w1);
    m[1][2] = fmaxf(m[1][2], bf2f(h1.z) * w1); m[1][3] = fmaxf(m[1][3], bf2f(h1.w) * w1);
    m[2][0] = fmaxf(m[2][0], bf2f(h2.x) * w2); m[2][1] = fmaxf(m[2][1], bf2f(h2.y) * w2);
    m[2][2] = fmaxf(m[2][2], bf2f(h2.z) * w2); m[2][3] = fmaxf(m[2][3], bf2f(h2.w) * w2);
    m[3][0] = fmaxf(m[3][0], bf2f(h3.x) * w3); m[3][1] = fmaxf(m[3][1], bf2f(h3.y) * w3);
    m[3][2] = fmaxf(m[3][2], bf2f(h3.z) * w3); m[3][3] = fmaxf(m[3][3], bf2f(h3.w) * w3);
  }
  for (; i < end; ++i) {
    int2 r0 = rec[i];
    short4 h0 = *(const short4*)(hp + (size_t)r0.x * D);
    float w0 = __int_as_float(r0.y);
    m[0][0] = fmaxf(m[0][0], bf2f(h0.x) * w0); m[0][1] = fmaxf(m[0][1], bf2f(h0.y) * w0);
    m[0][2] = fmaxf(m[0][2], bf2f(h0.z) * w0); m[0][3] = fmaxf(m[0][3], bf2f(h0.w) * w0);
  }
  short4 o;
  o.x = f2bf(fmaxf(fmaxf(m[0][0], m[1][0]), fmaxf(m[2][0], m[3][0])));
  o.y = f2bf(fmaxf(fmaxf(m[0][1], m[1][1]), fmaxf(m[2][1], m[3][1])));
  o.z = f2bf(fmaxf(fmaxf(m[0][2], m[1][2]), fmaxf(m[2][2], m[3][2])));
  o.w = f2bf(fmaxf(fmaxf(m[0][3], m[1][3]), fmaxf(m[2][3], m[3][3])));
  *(short4*)(agg + (size_t)dst * D + lane * 4) = o;
}

// ---- GEMM: out = relu( A1 @ W1 [+ A2 @ W2] + bias )
// Block = 64 rows x 256 cols, 4 waves. A1 fp32 (reg-staged: global->cvt->
// swizzled ds_write) or bf16 (global_load_lds DMA, inverse-swizzled source).
// A2 (if any) always bf16 via DMA. B pre-packed fragment-major, fully
// register-resident per wave (32 coalesced 16B loads).
template<typename TA1, int NSRC, int F32OUT>
__global__ __launch_bounds__(256, 2) void gemm_k(
    const TA1* __restrict__ A1, const short* __restrict__ B1p,
    const short* __restrict__ A2, const short* __restrict__ B2p,
    const float* __restrict__ bias, void* __restrict__ outp, int M)
{
  constexpr bool A1F = same_t<TA1, float>::v;
  __shared__ short smem[NSRC * 64 * 256];
  const int tid = threadIdx.x;
  const int wave = tid >> 6, lane = tid & 63;
  const int lr = lane & 15, kg = lane >> 4;
  const int m_base = blockIdx.x * 64;

  const short* Bs[2] = {B1p, B2p};

  // ---- DMA stages (issued first -> oldest in vmcnt FIFO)
  if constexpr (!A1F) {
#pragma unroll
    for (int it = 0; it < 8; ++it) {
      int L = it * 4096 + tid * 16;
      int row = L >> 9;
      int colb = (L & 511) ^ ((row & 7) << 4);
      int grow = m_base + row;
      grow = grow < M ? grow : M - 1;
      const char* gp = (const char*)A1 + (size_t)grow * 512 + colb;
      char* lp = (char*)smem + L;
      __builtin_amdgcn_global_load_lds((const glb_v*)gp, (lds_v*)lp, 16, 0, 0);
    }
  }
  if constexpr (NSRC == 2) {
#pragma unroll
    for (int it = 0; it < 8; ++it) {
      int L = it * 4096 + tid * 16;
      int row = L >> 9;
      int colb = (L & 511) ^ ((row & 7) << 4);
      int grow = m_base + row;
      grow = grow < M ? grow : M - 1;
      const char* gp = (const char*)A2 + (size_t)grow * 512 + colb;
      char* lp = (char*)smem + 32768 + L;
      __builtin_amdgcn_global_load_lds((const glb_v*)gp, (lds_v*)lp, 16, 0, 0);
    }
  }
  __builtin_amdgcn_sched_barrier(0);

  // ---- fp32 A1: reg-stage (16 independent loads, cvt, swizzled ds_write)
  if constexpr (A1F) {
    float4 fa[8][2];
#pragma unroll
    for (int it = 0; it < 8; ++it) {
      int L = it * 4096 + tid * 16;
      int row = L >> 9;
      int colel = (L & 511) >> 1;       // bf16 element index in row
      int grow = m_base + row;
      grow = grow < M ? grow : M - 1;
      const float* gp = A1 + (size_t)grow * D + colel;
      fa[it][0] = *(const float4*)gp;
      fa[it][1] = *(const float4*)(gp + 4);
    }
#pragma unroll
    for (int it = 0; it < 8; ++it) {
      int L = it * 4096 + tid * 16;
      int row = L >> 9;
      int Lw = L ^ ((row & 7) << 4);    // swizzled dest
      s16x8 o;
      o[0] = f2bf(fa[it][0].x); o[1] = f2bf(fa[it][0].y);
      o[2] = f2bf(fa[it][0].z); o[3] = f2bf(fa[it][0].w);
      o[4] = f2bf(fa[it][1].x); o[5] = f2bf(fa[it][1].y);
      o[6] = f2bf(fa[it][1].z); o[7] = f2bf(fa[it][1].w);
      *(s16x8*)((char*)smem + Lw) = o;
    }
    __builtin_amdgcn_sched_barrier(0);
  }

  f32x4 acc[4][4];
#pragma unroll
  for (int t = 0; t < 4; t++)
#pragma unroll
    for (int u = 0; u < 4; u++) acc[t][u] = (f32x4)(0.0f);

#pragma unroll
  for (int s = 0; s < NSRC; ++s) {
    // B panel resident: 32 coalesced 16B loads
    s16x8 breg[4][8];
#pragma unroll
    for (int u = 0; u < 4; ++u)
#pragma unroll
      for (int kc = 0; kc < 8; ++kc) {
        int g16 = wave * 4 + u;
        breg[u][kc] = *(const s16x8*)(Bs[s] + ((size_t)((g16 * 8 + kc) * 64 + lane)) * 8);
      }
    if (s == 0) {
      if constexpr (A1F && NSRC == 1) {
        // only ds_writes to drain; B loads stay in flight
        asm volatile("s_waitcnt lgkmcnt(0)" ::: "memory");
        __builtin_amdgcn_s_barrier();
        __builtin_amdgcn_sched_barrier(0);
      } else if constexpr (A1F && NSRC == 2) {
        __syncthreads();                 // drain DMA (vmcnt 0) + ds_writes
        __builtin_amdgcn_sched_barrier(0);
      } else {
        // DMAs (8*NSRC) are oldest; done when <=32 (B loads) outstanding
        asm volatile("s_waitcnt vmcnt(32)" ::: "memory");
        __builtin_amdgcn_s_barrier();
        __builtin_amdgcn_sched_barrier(0);
      }
    }
#pragma unroll
    for (int kc = 0; kc < 8; ++kc) {
      s16x8 a[4];
#pragma unroll
      for (int t = 0; t < 4; ++t) {
        int row = t * 16 + lr;
        int base = (row << 9) + kc * 64 + kg * 16;
        int off = s * 32768 + (base ^ ((row & 7) << 4));
        a[t] = *(const s16x8*)((const char*)smem + off);
      }
#pragma unroll
      for (int t = 0; t < 4; ++t)
#pragma unroll
        for (int u = 0; u < 4; ++u)
          acc[t][u] = __builtin_amdgcn_mfma_f32_16x16x32_bf16(a[t], breg[u][kc], acc[t][u], 0, 0, 0);
    }
  }

  // ---- epilogue: D layout col=lane&15, row=(lane>>4)*4+i
#pragma unroll
  for (int t = 0; t < 4; ++t) {
    int grow0 = m_base + t * 16 + kg * 4;
    if (m_base + t * 16 < M) {
#pragma unroll
      for (int u = 0; u < 4; ++u) {
        int col = wave * 64 + u * 16 + lr;
        float bv = bias[col];
#pragma unroll
        for (int i = 0; i < 4; ++i) {
          float v = acc[t][u][i] + bv;
          v = v > 0.0f ? v : 0.0f;
          size_t idx = (size_t)(grow0 + i) * D + col;
          if (F32OUT) ((float*)outp)[idx] = v;
          else        ((short*)outp)[idx] = f2bf(v);
        }
      }
    }
  }
}

extern "C" void kernel_launch(void* const* d_in, const int* in_sizes, int n_in,
                              void* d_out, int out_size, void* d_ws, size_t ws_size,
                              hipStream_t stream)
{
  const float* x    = (const float*)d_in[0];
  const int*   src0 = (const int*)d_in[1];
  const int*   dst0 = (const int*)d_in[2];
  const float* w0   = (const float*)d_in[3];
  const int*   src1 = (const int*)d_in[4];
  const int*   dst1 = (const int*)d_in[5];
  const float* w1   = (const float*)d_in[6];
  const float* Wp1  = (const float*)d_in[7];
  const float* bp1  = (const float*)d_in[8];
  const float* Ws1  = (const float*)d_in[9];
  const float* Wn1  = (const float*)d_in[10];
  const float* b1   = (const float*)d_in[11];
  const float* Wp2  = (const float*)d_in[12];
  const float* bp2  = (const float*)d_in[13];
  const float* Ws2  = (const float*)d_in[14];
  const float* Wn2  = (const float*)d_in[15];
  const float* b2   = (const float*)d_in[16];

  const int E0 = in_sizes[1], E1 = in_sizes[4];
  const int NCTR = N1C + N1C + N2C + N2C;   // cnt0, cur0, cnt1, cur1

  char* ws = (char*)d_ws;
  size_t off = 0;
  auto alloc = [&](size_t bytes) {
    void* p = ws + off;
    off += (bytes + 255) & ~(size_t)255;
    return p;
  };
  short* wp1t = (short*)alloc((size_t)D * D * 2);
  short* ws1t = (short*)alloc((size_t)D * D * 2);
  short* wn1t = (short*)alloc((size_t)D * D * 2);
  short* wp2t = (short*)alloc((size_t)D * D * 2);
  short* ws2t = (short*)alloc((size_t)D * D * 2);
  short* wn2t = (short*)alloc((size_t)D * D * 2);
  short* h1   = (short*)alloc((size_t)N0C * D * 2);
  short* h2   = (short*)alloc((size_t)N1C * D * 2);
  short* l1o  = (short*)alloc((size_t)N1C * D * 2);
  short* agg1 = (short*)alloc((size_t)N1C * D * 2);
  short* agg2 = (short*)alloc((size_t)N2C * D * 2);
  int*   ctrs = (int*)alloc((size_t)NCTR * 4);   // one contiguous block
  int*   cnt0 = ctrs;
  int*   cur0 = ctrs + N1C;
  int*   cnt1 = ctrs + 2 * N1C;
  int*   cur1 = ctrs + 2 * N1C + N2C;
  int*   off0 = (int*)alloc((size_t)(N1C + 1) * 4);
  int*   off1 = (int*)alloc((size_t)(N2C + 1) * 4);
  int2*  rec0 = (int2*)alloc((size_t)E0 * 8);
  int2*  rec1 = (int2*)alloc((size_t)E1 * 8);

  // weights -> fragment-major bf16; also zeroes ctrs (49152 threads >= NCTR)
  wtransp_k<<<dim3(32, 6), 256, 0, stream>>>(Wp1, Ws1, Wn1, Wp2, Ws2, Wn2,
                                             wp1t, ws1t, wn1t, wp2t, ws2t, wn2t,
                                             ctrs, NCTR);

  int eb = (E0 + E1 + 255) / 256;
  hist_k<<<eb, 256, 0, stream>>>(dst0, E0, cnt0, dst1, E1, cnt1);
  scan_k<<<2, 256, 0, stream>>>(cnt0, off0, N1C, cnt1, off1, N2C);
  scat_k<<<eb, 256, 0, stream>>>(src0, dst0, w0, E0, off0, cur0, rec0,
                                 src1, dst1, w1, E1, off1, cur1, rec1);

  // h1 = relu(x @ Wp1 + bp1) -> bf16   (A = fp32 x, reg-staged cvt)
  gemm_k<float, 1, 0><<<(N0C + 63) / 64, 256, 0, stream>>>(
      x, wp1t, (const short*)nullptr, nullptr, bp1, h1, N0C);
  // agg1 = segment_max(h1[src0]*w0, dst0) -> bf16
  seg_max_k<<<(N1C + 3) / 4, 256, 0, stream>>>(h1, off0, rec0, agg1, N1C);
  // l1o = relu(x[:N1] @ Ws1 + agg1 @ Wn1 + b1) -> bf16
  gemm_k<float, 2, 0><<<(N1C + 63) / 64, 256, 0, stream>>>(
      x, ws1t, agg1, wn1t, b1, l1o, N1C);
  // h2 = relu(l1o @ Wp2 + bp2) -> bf16
  gemm_k<short, 1, 0><<<(N1C + 63) / 64, 256, 0, stream>>>(
      l1o, wp2t, (const short*)nullptr, nullptr, bp2, h2, N1C);
  // agg2 = segment_max(h2[src1]*w1, dst1) -> bf16
  seg_max_k<<<(N2C + 3) / 4, 256, 0, stream>>>(h2, off1, rec1, agg2, N2C);
  // out = relu(l1o[:N2] @ Ws2 + agg2 @ Wn2 + b2) -> fp32
  gemm_k<short, 2, 1><<<(N2C + 63) / 64, 256, 0, stream>>>(
      l1o, ws2t, agg2, wn2t, b2, d_out, N2C);
}

// Round 7
// 220.754 us; speedup vs baseline: 8.2393x; 1.0564x over previous
//
#include <hip/hip_runtime.h>
#include <hip/hip_bf16.h>

#define D 256
#define N0C 100000
#define N1C 20000
#define N2C 4000

typedef short s16x8 __attribute__((ext_vector_type(8)));
typedef float f32x4 __attribute__((ext_vector_type(4)));

typedef __attribute__((address_space(3))) void lds_v;
typedef __attribute__((address_space(1))) void glb_v;

template<class A, class B> struct same_t { static constexpr bool v = false; };
template<class A> struct same_t<A, A> { static constexpr bool v = true; };

__device__ __forceinline__ short f2bf(float f) {
  __hip_bfloat16 b = __float2bfloat16(f);   // RNE hardware cvt
  union { __hip_bfloat16 h; short s; } u;
  u.h = b;
  return u.s;
}
__device__ __forceinline__ float bf2f(short s) {
  return __uint_as_float(((unsigned)(unsigned short)s) << 16);
}

// ---- weight -> fragment-major packed bf16 (+ zero the CSR counters).
// chunk c (0..8191): lane=c&63, kc=(c>>6)&7, g16=c>>9.
// chunk holds B-frag for MFMA 16x16x32: col=g16*16+(lane&15), k=kc*32+(lane>>4)*8+j
__global__ __launch_bounds__(256) void wtransp_k(
    const float* __restrict__ W0, const float* __restrict__ W1,
    const float* __restrict__ W2, const float* __restrict__ W3,
    const float* __restrict__ W4, const float* __restrict__ W5,
    short* __restrict__ T0, short* __restrict__ T1, short* __restrict__ T2,
    short* __restrict__ T3, short* __restrict__ T4, short* __restrict__ T5,
    int* __restrict__ ctrs, int nctr)
{
  int flat = (blockIdx.y * gridDim.x + blockIdx.x) * 256 + threadIdx.x;
  if (flat < nctr) ctrs[flat] = 0;

  const float* Ws[6] = {W0, W1, W2, W3, W4, W5};
  short* Ts[6] = {T0, T1, T2, T3, T4, T5};
  int g = blockIdx.y;
  int c = blockIdx.x * 256 + threadIdx.x;  // 0..8191
  int lane = c & 63, kc = (c >> 6) & 7, g16 = c >> 9;
  int col = g16 * 16 + (lane & 15);
  int kbase = kc * 32 + (lane >> 4) * 8;
  const float* W = Ws[g];
  s16x8 o;
#pragma unroll
  for (int j = 0; j < 8; ++j) o[j] = f2bf(W[(size_t)(kbase + j) * D + col]);
  *(s16x8*)(Ts[g] + (size_t)c * 8) = o;
}

// ---- CSR build
__global__ __launch_bounds__(256) void hist_k(
    const int* __restrict__ dst0, int E0, int* __restrict__ c0,
    const int* __restrict__ dst1, int E1, int* __restrict__ c1)
{
  int i = blockIdx.x * 256 + threadIdx.x;
  if (i < E0) atomicAdd(&c0[dst0[i]], 1);
  else if (i < E0 + E1) atomicAdd(&c1[dst1[i - E0]], 1);
}

// 1024 threads, 2 blocks (block 0: graph0, block 1: graph1)
__global__ __launch_bounds__(1024) void scan_k(
    const int* __restrict__ c0, int* __restrict__ o0, int n0,
    const int* __restrict__ c1, int* __restrict__ o1, int n1)
{
  const int* c = blockIdx.x ? c1 : c0;
  int* o = blockIdx.x ? o1 : o0;
  int n = blockIdx.x ? n1 : n0;
  __shared__ int lsum[1024];
  int t = threadIdx.x;
  int chunk = (n + 1023) / 1024;
  int beg = t * chunk, end = min(beg + chunk, n);
  int s = 0;
  for (int i = beg; i < end; ++i) s += c[i];
  lsum[t] = s;
  __syncthreads();
  for (int d = 1; d < 1024; d <<= 1) {
    int v = (t >= d) ? lsum[t - d] : 0;
    __syncthreads();
    lsum[t] += v;
    __syncthreads();
  }
  int run = (t == 0) ? 0 : lsum[t - 1];
  for (int i = beg; i < end; ++i) { o[i] = run; run += c[i]; }
  if (t == 1023) o[n] = run;
}

__global__ __launch_bounds__(256) void scat_k(
    const int* __restrict__ src0, const int* __restrict__ dst0,
    const float* __restrict__ w0, int E0, const int* __restrict__ offs0,
    int* __restrict__ cur0, int2* __restrict__ rec0,
    const int* __restrict__ src1, const int* __restrict__ dst1,
    const float* __restrict__ w1, int E1, const int* __restrict__ offs1,
    int* __restrict__ cur1, int2* __restrict__ rec1)
{
  int i = blockIdx.x * 256 + threadIdx.x;
  if (i < E0) {
    int d = dst0[i];
    int p = offs0[d] + atomicAdd(&cur0[d], 1);
    rec0[p] = make_int2(src0[i], __float_as_int(w0[i]));
  } else if (i < E0 + E1) {
    int j = i - E0;
    int d = dst1[j];
    int p = offs1[d] + atomicAdd(&cur1[d], 1);
    rec1[p] = make_int2(src1[j], __float_as_int(w1[j]));
  }
}

// ---- per-dst gather max: one wave per dst, 64 lanes x 4 dims, 8-edge unroll
__global__ __launch_bounds__(256) void seg_max_k(
    const short* __restrict__ h, const int* __restrict__ offs,
    const int2* __restrict__ rec, short* __restrict__ agg, int ndst)
{
  int dst = blockIdx.x * 4 + (threadIdx.x >> 6);
  if (dst >= ndst) return;
  int lane = threadIdx.x & 63;
  int beg = offs[dst], end = offs[dst + 1];
  const short* hp = h + (size_t)lane * 4;
  float m[8][4];
#pragma unroll
  for (int j = 0; j < 8; j++)
#pragma unroll
    for (int d2 = 0; d2 < 4; d2++) m[j][d2] = 0.f;
  int i = beg;
  for (; i + 7 < end; i += 8) {
    int2 r[8];
    short4 hv[8];
#pragma unroll
    for (int j = 0; j < 8; ++j) r[j] = rec[i + j];
#pragma unroll
    for (int j = 0; j < 8; ++j) hv[j] = *(const short4*)(hp + (size_t)r[j].x * D);
#pragma unroll
    for (int j = 0; j < 8; ++j) {
      float w = __int_as_float(r[j].y);
      m[j][0] = fmaxf(m[j][0], bf2f(hv[j].x) * w);
      m[j][1] = fmaxf(m[j][1], bf2f(hv[j].y) * w);
      m[j][2] = fmaxf(m[j][2], bf2f(hv[j].z) * w);
      m[j][3] = fmaxf(m[j][3], bf2f(hv[j].w) * w);
    }
  }
  for (; i < end; ++i) {
    int2 r0 = rec[i];
    short4 h0 = *(const short4*)(hp + (size_t)r0.x * D);
    float w0 = __int_as_float(r0.y);
    m[0][0] = fmaxf(m[0][0], bf2f(h0.x) * w0); m[0][1] = fmaxf(m[0][1], bf2f(h0.y) * w0);
    m[0][2] = fmaxf(m[0][2], bf2f(h0.z) * w0); m[0][3] = fmaxf(m[0][3], bf2f(h0.w) * w0);
  }
#pragma unroll
  for (int j = 1; j < 8; ++j)
#pragma unroll
    for (int d2 = 0; d2 < 4; d2++) m[0][d2] = fmaxf(m[0][d2], m[j][d2]);
  short4 o;
  o.x = f2bf(m[0][0]); o.y = f2bf(m[0][1]);
  o.z = f2bf(m[0][2]); o.w = f2bf(m[0][3]);
  *(short4*)(agg + (size_t)dst * D + lane * 4) = o;
}

// ---- GEMM: out = relu( A1 @ W1 [+ A2 @ W2] + bias )
// Block = 64 rows x 256 cols, 4 waves. A1 fp32 (reg-staged: global->cvt->
// swizzled ds_write) or bf16 (global_load_lds DMA, inverse-swizzled source).
// A2 (if any) always bf16 via DMA. B pre-packed fragment-major, fully
// register-resident per wave (32 coalesced 16B loads).
template<typename TA1, int NSRC, int F32OUT>
__global__ __launch_bounds__(256, 2) void gemm_k(
    const TA1* __restrict__ A1, const short* __restrict__ B1p,
    const short* __restrict__ A2, const short* __restrict__ B2p,
    const float* __restrict__ bias, void* __restrict__ outp, int M)
{
  constexpr bool A1F = same_t<TA1, float>::v;
  __shared__ short smem[NSRC * 64 * 256];
  const int tid = threadIdx.x;
  const int wave = tid >> 6, lane = tid & 63;
  const int lr = lane & 15, kg = lane >> 4;
  const int m_base = blockIdx.x * 64;

  const short* Bs[2] = {B1p, B2p};

  // ---- DMA stages (issued first -> oldest in vmcnt FIFO)
  if constexpr (!A1F) {
#pragma unroll
    for (int it = 0; it < 8; ++it) {
      int L = it * 4096 + tid * 16;
      int row = L >> 9;
      int colb = (L & 511) ^ ((row & 7) << 4);
      int grow = m_base + row;
      grow = grow < M ? grow : M - 1;
      const char* gp = (const char*)A1 + (size_t)grow * 512 + colb;
      char* lp = (char*)smem + L;
      __builtin_amdgcn_global_load_lds((const glb_v*)gp, (lds_v*)lp, 16, 0, 0);
    }
  }
  if constexpr (NSRC == 2) {
#pragma unroll
    for (int it = 0; it < 8; ++it) {
      int L = it * 4096 + tid * 16;
      int row = L >> 9;
      int colb = (L & 511) ^ ((row & 7) << 4);
      int grow = m_base + row;
      grow = grow < M ? grow : M - 1;
      const char* gp = (const char*)A2 + (size_t)grow * 512 + colb;
      char* lp = (char*)smem + 32768 + L;
      __builtin_amdgcn_global_load_lds((const glb_v*)gp, (lds_v*)lp, 16, 0, 0);
    }
  }
  __builtin_amdgcn_sched_barrier(0);

  // ---- fp32 A1: reg-stage (16 independent loads, cvt, swizzled ds_write)
  if constexpr (A1F) {
    float4 fa[8][2];
#pragma unroll
    for (int it = 0; it < 8; ++it) {
      int L = it * 4096 + tid * 16;
      int row = L >> 9;
      int colel = (L & 511) >> 1;       // bf16 element index in row
      int grow = m_base + row;
      grow = grow < M ? grow : M - 1;
      const float* gp = A1 + (size_t)grow * D + colel;
      fa[it][0] = *(const float4*)gp;
      fa[it][1] = *(const float4*)(gp + 4);
    }
#pragma unroll
    for (int it = 0; it < 8; ++it) {
      int L = it * 4096 + tid * 16;
      int row = L >> 9;
      int Lw = L ^ ((row & 7) << 4);    // swizzled dest
      s16x8 o;
      o[0] = f2bf(fa[it][0].x); o[1] = f2bf(fa[it][0].y);
      o[2] = f2bf(fa[it][0].z); o[3] = f2bf(fa[it][0].w);
      o[4] = f2bf(fa[it][1].x); o[5] = f2bf(fa[it][1].y);
      o[6] = f2bf(fa[it][1].z); o[7] = f2bf(fa[it][1].w);
      *(s16x8*)((char*)smem + Lw) = o;
    }
    __builtin_amdgcn_sched_barrier(0);
  }

  f32x4 acc[4][4];
#pragma unroll
  for (int t = 0; t < 4; t++)
#pragma unroll
    for (int u = 0; u < 4; u++) acc[t][u] = (f32x4)(0.0f);

#pragma unroll
  for (int s = 0; s < NSRC; ++s) {
    // B panel resident: 32 coalesced 16B loads
    s16x8 breg[4][8];
#pragma unroll
    for (int u = 0; u < 4; ++u)
#pragma unroll
      for (int kc = 0; kc < 8; ++kc) {
        int g16 = wave * 4 + u;
        breg[u][kc] = *(const s16x8*)(Bs[s] + ((size_t)((g16 * 8 + kc) * 64 + lane)) * 8);
      }
    if (s == 0) {
      if constexpr (A1F && NSRC == 1) {
        // only ds_writes to drain; B loads stay in flight
        asm volatile("s_waitcnt lgkmcnt(0)" ::: "memory");
        __builtin_amdgcn_s_barrier();
        __builtin_amdgcn_sched_barrier(0);
      } else if constexpr (A1F && NSRC == 2) {
        __syncthreads();                 // drain DMA (vmcnt 0) + ds_writes
        __builtin_amdgcn_sched_barrier(0);
      } else {
        // DMAs (8*NSRC) are oldest; done when <=32 (B loads) outstanding
        asm volatile("s_waitcnt vmcnt(32)" ::: "memory");
        __builtin_amdgcn_s_barrier();
        __builtin_amdgcn_sched_barrier(0);
      }
    }
#pragma unroll
    for (int kc = 0; kc < 8; ++kc) {
      s16x8 a[4];
#pragma unroll
      for (int t = 0; t < 4; ++t) {
        int row = t * 16 + lr;
        int base = (row << 9) + kc * 64 + kg * 16;
        int off = s * 32768 + (base ^ ((row & 7) << 4));
        a[t] = *(const s16x8*)((const char*)smem + off);
      }
#pragma unroll
      for (int t = 0; t < 4; ++t)
#pragma unroll
        for (int u = 0; u < 4; ++u)
          acc[t][u] = __builtin_amdgcn_mfma_f32_16x16x32_bf16(a[t], breg[u][kc], acc[t][u], 0, 0, 0);
    }
  }

  // ---- epilogue: D layout col=lane&15, row=(lane>>4)*4+i
#pragma unroll
  for (int t = 0; t < 4; ++t) {
    int grow0 = m_base + t * 16 + kg * 4;
    if (m_base + t * 16 < M) {
#pragma unroll
      for (int u = 0; u < 4; ++u) {
        int col = wave * 64 + u * 16 + lr;
        float bv = bias[col];
#pragma unroll
        for (int i = 0; i < 4; ++i) {
          float v = acc[t][u][i] + bv;
          v = v > 0.0f ? v : 0.0f;
          size_t idx = (size_t)(grow0 + i) * D + col;
          if (F32OUT) ((float*)outp)[idx] = v;
          else        ((short*)outp)[idx] = f2bf(v);
        }
      }
    }
  }
}

// ---- FUSED layer-1 dst GEMM + layer-2 pre GEMM:
//   l1o = relu( X @ Ws1 + agg1 @ Wn1 + b1 )   [write only rows < LROWS]
//   h2  = relu( l1o @ Wp2 + bp2 )
// Stage-1 identical to gemm_k<float,2,0>. Then l1o panel (64x256, in acc)
// is written to LDS (swizzled, same layout as A-tiles) and consumed by
// stage-2 MFMAs -- l1o never re-read from HBM.
__global__ __launch_bounds__(256, 2) void gemm23_k(
    const float* __restrict__ X, const short* __restrict__ Bs1,
    const short* __restrict__ A2, const short* __restrict__ Bn1,
    const short* __restrict__ Bp2,
    const float* __restrict__ b1, const float* __restrict__ bp2,
    short* __restrict__ l1o, short* __restrict__ h2, int M, int LROWS)
{
  __shared__ short smem[2 * 64 * 256];
  const int tid = threadIdx.x;
  const int wave = tid >> 6, lane = tid & 63;
  const int lr = lane & 15, kg = lane >> 4;
  const int m_base = blockIdx.x * 64;

  const short* Bs[2] = {Bs1, Bn1};

  // DMA agg1 tile -> smem[1]
#pragma unroll
  for (int it = 0; it < 8; ++it) {
    int L = it * 4096 + tid * 16;
    int row = L >> 9;
    int colb = (L & 511) ^ ((row & 7) << 4);
    int grow = m_base + row;
    grow = grow < M ? grow : M - 1;
    const char* gp = (const char*)A2 + (size_t)grow * 512 + colb;
    char* lp = (char*)smem + 32768 + L;
    __builtin_amdgcn_global_load_lds((const glb_v*)gp, (lds_v*)lp, 16, 0, 0);
  }
  __builtin_amdgcn_sched_barrier(0);

  // fp32 X reg-stage -> smem[0]
  {
    float4 fa[8][2];
#pragma unroll
    for (int it = 0; it < 8; ++it) {
      int L = it * 4096 + tid * 16;
      int row = L >> 9;
      int colel = (L & 511) >> 1;
      int grow = m_base + row;
      grow = grow < M ? grow : M - 1;
      const float* gp = X + (size_t)grow * D + colel;
      fa[it][0] = *(const float4*)gp;
      fa[it][1] = *(const float4*)(gp + 4);
    }
#pragma unroll
    for (int it = 0; it < 8; ++it) {
      int L = it * 4096 + tid * 16;
      int row = L >> 9;
      int Lw = L ^ ((row & 7) << 4);
      s16x8 o;
      o[0] = f2bf(fa[it][0].x); o[1] = f2bf(fa[it][0].y);
      o[2] = f2bf(fa[it][0].z); o[3] = f2bf(fa[it][0].w);
      o[4] = f2bf(fa[it][1].x); o[5] = f2bf(fa[it][1].y);
      o[6] = f2bf(fa[it][1].z); o[7] = f2bf(fa[it][1].w);
      *(s16x8*)((char*)smem + Lw) = o;
    }
    __builtin_amdgcn_sched_barrier(0);
  }

  f32x4 acc[4][4];
#pragma unroll
  for (int t = 0; t < 4; t++)
#pragma unroll
    for (int u = 0; u < 4; u++) acc[t][u] = (f32x4)(0.0f);

#pragma unroll
  for (int s = 0; s < 2; ++s) {
    s16x8 breg[4][8];
#pragma unroll
    for (int u = 0; u < 4; ++u)
#pragma unroll
      for (int kc = 0; kc < 8; ++kc) {
        int g16 = wave * 4 + u;
        breg[u][kc] = *(const s16x8*)(Bs[s] + ((size_t)((g16 * 8 + kc) * 64 + lane)) * 8);
      }
    if (s == 0) {
      __syncthreads();                 // drain DMA + ds_writes
      __builtin_amdgcn_sched_barrier(0);
    }
#pragma unroll
    for (int kc = 0; kc < 8; ++kc) {
      s16x8 a[4];
#pragma unroll
      for (int t = 0; t < 4; ++t) {
        int row = t * 16 + lr;
        int base = (row << 9) + kc * 64 + kg * 16;
        int off = s * 32768 + (base ^ ((row & 7) << 4));
        a[t] = *(const s16x8*)((const char*)smem + off);
      }
#pragma unroll
      for (int t = 0; t < 4; ++t)
#pragma unroll
        for (int u = 0; u < 4; ++u)
          acc[t][u] = __builtin_amdgcn_mfma_f32_16x16x32_bf16(a[t], breg[u][kc], acc[t][u], 0, 0, 0);
    }
  }

  // all waves done reading smem -> safe to reuse smem[0] for l1o tile
  __builtin_amdgcn_s_barrier();
  __builtin_amdgcn_sched_barrier(0);

  // issue Wp2 panel loads (in flight across epilogue-1)
  s16x8 breg2[4][8];
#pragma unroll
  for (int u = 0; u < 4; ++u)
#pragma unroll
    for (int kc = 0; kc < 8; ++kc) {
      int g16 = wave * 4 + u;
      breg2[u][kc] = *(const s16x8*)(Bp2 + ((size_t)((g16 * 8 + kc) * 64 + lane)) * 8);
    }

  // epilogue-1: l1o = relu(acc+b1); global write (rows<LROWS) + LDS write
#pragma unroll
  for (int t = 0; t < 4; ++t)
#pragma unroll
    for (int u = 0; u < 4; ++u) {
      int col = wave * 64 + u * 16 + lr;
      float bv = b1[col];
#pragma unroll
      for (int i = 0; i < 4; ++i) {
        int r = t * 16 + kg * 4 + i;   // block-local row
        float v = acc[t][u][i] + bv;
        v = v > 0.0f ? v : 0.0f;
        short sv = f2bf(v);
        int grow = m_base + r;
        if (grow < LROWS) l1o[(size_t)grow * D + col] = sv;
        int ba = ((r << 9) + 2 * col) ^ ((r & 7) << 4);
        *(short*)((char*)smem + ba) = sv;
      }
    }
  asm volatile("s_waitcnt lgkmcnt(0)" ::: "memory");
  __builtin_amdgcn_s_barrier();
  __builtin_amdgcn_sched_barrier(0);

  // stage-2: h2 = relu(l1o @ Wp2 + bp2)
  f32x4 acc2[4][4];
#pragma unroll
  for (int t = 0; t < 4; t++)
#pragma unroll
    for (int u = 0; u < 4; u++) acc2[t][u] = (f32x4)(0.0f);
#pragma unroll
  for (int kc = 0; kc < 8; ++kc) {
    s16x8 a[4];
#pragma unroll
    for (int t = 0; t < 4; ++t) {
      int row = t * 16 + lr;
      int base = (row << 9) + kc * 64 + kg * 16;
      int off = base ^ ((row & 7) << 4);
      a[t] = *(const s16x8*)((const char*)smem + off);
    }
#pragma unroll
    for (int t = 0; t < 4; ++t)
#pragma unroll
      for (int u = 0; u < 4; ++u)
        acc2[t][u] = __builtin_amdgcn_mfma_f32_16x16x32_bf16(a[t], breg2[u][kc], acc2[t][u], 0, 0, 0);
  }

#pragma unroll
  for (int t = 0; t < 4; ++t) {
    int grow0 = m_base + t * 16 + kg * 4;
    if (m_base + t * 16 < M) {
#pragma unroll
      for (int u = 0; u < 4; ++u) {
        int col = wave * 64 + u * 16 + lr;
        float bv = bp2[col];
#pragma unroll
        for (int i = 0; i < 4; ++i) {
          float v = acc2[t][u][i] + bv;
          v = v > 0.0f ? v : 0.0f;
          h2[(size_t)(grow0 + i) * D + col] = f2bf(v);
        }
      }
    }
  }
}

extern "C" void kernel_launch(void* const* d_in, const int* in_sizes, int n_in,
                              void* d_out, int out_size, void* d_ws, size_t ws_size,
                              hipStream_t stream)
{
  const float* x    = (const float*)d_in[0];
  const int*   src0 = (const int*)d_in[1];
  const int*   dst0 = (const int*)d_in[2];
  const float* w0   = (const float*)d_in[3];
  const int*   src1 = (const int*)d_in[4];
  const int*   dst1 = (const int*)d_in[5];
  const float* w1   = (const float*)d_in[6];
  const float* Wp1  = (const float*)d_in[7];
  const float* bp1  = (const float*)d_in[8];
  const float* Ws1  = (const float*)d_in[9];
  const float* Wn1  = (const float*)d_in[10];
  const float* b1   = (const float*)d_in[11];
  const float* Wp2  = (const float*)d_in[12];
  const float* bp2  = (const float*)d_in[13];
  const float* Ws2  = (const float*)d_in[14];
  const float* Wn2  = (const float*)d_in[15];
  const float* b2   = (const float*)d_in[16];

  const int E0 = in_sizes[1], E1 = in_sizes[4];
  const int NCTR = N1C + N1C + N2C + N2C;   // cnt0, cur0, cnt1, cur1

  char* ws = (char*)d_ws;
  size_t off = 0;
  auto alloc = [&](size_t bytes) {
    void* p = ws + off;
    off += (bytes + 255) & ~(size_t)255;
    return p;
  };
  short* wp1t = (short*)alloc((size_t)D * D * 2);
  short* ws1t = (short*)alloc((size_t)D * D * 2);
  short* wn1t = (short*)alloc((size_t)D * D * 2);
  short* wp2t = (short*)alloc((size_t)D * D * 2);
  short* ws2t = (short*)alloc((size_t)D * D * 2);
  short* wn2t = (short*)alloc((size_t)D * D * 2);
  short* h1   = (short*)alloc((size_t)N0C * D * 2);
  short* h2   = (short*)alloc((size_t)N1C * D * 2);
  short* l1o  = (short*)alloc((size_t)N2C * D * 2);   // only first 4000 rows needed
  short* agg1 = (short*)alloc((size_t)N1C * D * 2);
  short* agg2 = (short*)alloc((size_t)N2C * D * 2);
  int*   ctrs = (int*)alloc((size_t)NCTR * 4);   // one contiguous block
  int*   cnt0 = ctrs;
  int*   cur0 = ctrs + N1C;
  int*   cnt1 = ctrs + 2 * N1C;
  int*   cur1 = ctrs + 2 * N1C + N2C;
  int*   off0 = (int*)alloc((size_t)(N1C + 1) * 4);
  int*   off1 = (int*)alloc((size_t)(N2C + 1) * 4);
  int2*  rec0 = (int2*)alloc((size_t)E0 * 8);
  int2*  rec1 = (int2*)alloc((size_t)E1 * 8);

  // weights -> fragment-major bf16; also zeroes ctrs (49152 threads >= NCTR)
  wtransp_k<<<dim3(32, 6), 256, 0, stream>>>(Wp1, Ws1, Wn1, Wp2, Ws2, Wn2,
                                             wp1t, ws1t, wn1t, wp2t, ws2t, wn2t,
                                             ctrs, NCTR);

  int eb = (E0 + E1 + 255) / 256;
  hist_k<<<eb, 256, 0, stream>>>(dst0, E0, cnt0, dst1, E1, cnt1);
  scan_k<<<2, 1024, 0, stream>>>(cnt0, off0, N1C, cnt1, off1, N2C);
  scat_k<<<eb, 256, 0, stream>>>(src0, dst0, w0, E0, off0, cur0, rec0,
                                 src1, dst1, w1, E1, off1, cur1, rec1);

  // h1 = relu(x @ Wp1 + bp1) -> bf16   (A = fp32 x, reg-staged cvt)
  gemm_k<float, 1, 0><<<(N0C + 63) / 64, 256, 0, stream>>>(
      x, wp1t, (const short*)nullptr, nullptr, bp1, h1, N0C);
  // agg1 = segment_max(h1[src0]*w0, dst0) -> bf16
  seg_max_k<<<(N1C + 3) / 4, 256, 0, stream>>>(h1, off0, rec0, agg1, N1C);
  // FUSED: l1o = relu(x@Ws1 + agg1@Wn1 + b1) [rows<4000 to HBM]
  //        h2  = relu(l1o @ Wp2 + bp2)
  gemm23_k<<<(N1C + 63) / 64, 256, 0, stream>>>(
      x, ws1t, agg1, wn1t, wp2t, b1, bp2, l1o, h2, N1C, N2C);
  // agg2 = segment_max(h2[src1]*w1, dst1) -> bf16
  seg_max_k<<<(N2C + 3) / 4, 256, 0, stream>>>(h2, off1, rec1, agg2, N2C);
  // out = relu(l1o[:N2] @ Ws2 + agg2 @ Wn2 + b2) -> fp32
  gemm_k<short, 2, 1><<<(N2C + 63) / 64, 256, 0, stream>>>(
      l1o, ws2t, agg2, wn2t, b2, d_out, N2C);
}

// Round 8
// 206.615 us; speedup vs baseline: 8.8030x; 1.0684x over previous
//
#include <hip/hip_runtime.h>
#include <hip/hip_bf16.h>

#define D 256
#define N0C 100000
#define N1C 20000
#define N2C 4000
#define BCAP 64
#define OVFCAP 4096

typedef short s16x8 __attribute__((ext_vector_type(8)));
typedef float f32x4 __attribute__((ext_vector_type(4)));

typedef __attribute__((address_space(3))) void lds_v;
typedef __attribute__((address_space(1))) void glb_v;

template<class A, class B> struct same_t { static constexpr bool v = false; };
template<class A> struct same_t<A, A> { static constexpr bool v = true; };

__device__ __forceinline__ short f2bf(float f) {
  __hip_bfloat16 b = __float2bfloat16(f);   // RNE hardware cvt
  union { __hip_bfloat16 h; short s; } u;
  u.h = b;
  return u.s;
}
__device__ __forceinline__ float bf2f(short s) {
  return __uint_as_float(((unsigned)(unsigned short)s) << 16);
}

// ---- weight -> fragment-major packed bf16 (+ zero bucket counters).
// chunk c (0..8191): lane=c&63, kc=(c>>6)&7, g16=c>>9.
// chunk holds B-frag for MFMA 16x16x32: col=g16*16+(lane&15), k=kc*32+(lane>>4)*8+j
__global__ __launch_bounds__(256) void wtransp_k(
    const float* __restrict__ W0, const float* __restrict__ W1,
    const float* __restrict__ W2, const float* __restrict__ W3,
    const float* __restrict__ W4, const float* __restrict__ W5,
    short* __restrict__ T0, short* __restrict__ T1, short* __restrict__ T2,
    short* __restrict__ T3, short* __restrict__ T4, short* __restrict__ T5,
    int* __restrict__ ctrs, int nctr)
{
  int flat = (blockIdx.y * gridDim.x + blockIdx.x) * 256 + threadIdx.x;
  if (flat < nctr) ctrs[flat] = 0;

  const float* Ws[6] = {W0, W1, W2, W3, W4, W5};
  short* Ts[6] = {T0, T1, T2, T3, T4, T5};
  int g = blockIdx.y;
  int c = blockIdx.x * 256 + threadIdx.x;  // 0..8191
  int lane = c & 63, kc = (c >> 6) & 7, g16 = c >> 9;
  int col = g16 * 16 + (lane & 15);
  int kbase = kc * 32 + (lane >> 4) * 8;
  const float* W = Ws[g];
  s16x8 o;
#pragma unroll
  for (int j = 0; j < 8; ++j) o[j] = f2bf(W[(size_t)(kbase + j) * D + col]);
  *(s16x8*)(Ts[g] + (size_t)c * 8) = o;
}

// ---- direct-bucket edge scatter: rec[dst*BCAP + slot] = (src, wbits).
// slot >= BCAP spills to overflow array (statistically never for Poisson(25)).
__global__ __launch_bounds__(256) void scat_direct_k(
    const int* __restrict__ src0, const int* __restrict__ dst0,
    const float* __restrict__ w0, int E0, int* __restrict__ cur0,
    int2* __restrict__ rec0, int* __restrict__ ovfc0, int4* __restrict__ ovf0,
    const int* __restrict__ src1, const int* __restrict__ dst1,
    const float* __restrict__ w1, int E1, int* __restrict__ cur1,
    int2* __restrict__ rec1, int* __restrict__ ovfc1, int4* __restrict__ ovf1)
{
  int i = blockIdx.x * 256 + threadIdx.x;
  if (i < E0) {
    int d = dst0[i];
    int p = atomicAdd(&cur0[d], 1);
    if (p < BCAP) rec0[d * BCAP + p] = make_int2(src0[i], __float_as_int(w0[i]));
    else {
      int q = atomicAdd(ovfc0, 1);
      if (q < OVFCAP) ovf0[q] = make_int4(d, src0[i], __float_as_int(w0[i]), 0);
    }
  } else if (i < E0 + E1) {
    int j = i - E0;
    int d = dst1[j];
    int p = atomicAdd(&cur1[d], 1);
    if (p < BCAP) rec1[d * BCAP + p] = make_int2(src1[j], __float_as_int(w1[j]));
    else {
      int q = atomicAdd(ovfc1, 1);
      if (q < OVFCAP) ovf1[q] = make_int4(d, src1[j], __float_as_int(w1[j]), 0);
    }
  }
}

// ---- per-dst gather max: one wave per dst, 64 lanes x 4 dims, 8-edge unroll.
// Reads its fixed-capacity bucket; then scans the (normally empty) overflow.
__global__ __launch_bounds__(256) void seg_max_k(
    const short* __restrict__ h, const int* __restrict__ cur,
    const int2* __restrict__ rec, const int* __restrict__ ovfc,
    const int4* __restrict__ ovf, short* __restrict__ agg, int ndst)
{
  int dst = blockIdx.x * 4 + (threadIdx.x >> 6);
  if (dst >= ndst) return;
  int lane = threadIdx.x & 63;
  int cnt = cur[dst];
  cnt = cnt < BCAP ? cnt : BCAP;
  const int2* bp = rec + (size_t)dst * BCAP;
  const short* hp = h + (size_t)lane * 4;
  float m[8][4];
#pragma unroll
  for (int j = 0; j < 8; j++)
#pragma unroll
    for (int d2 = 0; d2 < 4; d2++) m[j][d2] = 0.f;
  int i = 0;
  for (; i + 7 < cnt; i += 8) {
    int2 r[8];
    short4 hv[8];
#pragma unroll
    for (int j = 0; j < 8; ++j) r[j] = bp[i + j];
#pragma unroll
    for (int j = 0; j < 8; ++j) hv[j] = *(const short4*)(hp + (size_t)r[j].x * D);
#pragma unroll
    for (int j = 0; j < 8; ++j) {
      float w = __int_as_float(r[j].y);
      m[j][0] = fmaxf(m[j][0], bf2f(hv[j].x) * w);
      m[j][1] = fmaxf(m[j][1], bf2f(hv[j].y) * w);
      m[j][2] = fmaxf(m[j][2], bf2f(hv[j].z) * w);
      m[j][3] = fmaxf(m[j][3], bf2f(hv[j].w) * w);
    }
  }
  for (; i < cnt; ++i) {
    int2 r0 = bp[i];
    short4 h0 = *(const short4*)(hp + (size_t)r0.x * D);
    float w0 = __int_as_float(r0.y);
    m[0][0] = fmaxf(m[0][0], bf2f(h0.x) * w0); m[0][1] = fmaxf(m[0][1], bf2f(h0.y) * w0);
    m[0][2] = fmaxf(m[0][2], bf2f(h0.z) * w0); m[0][3] = fmaxf(m[0][3], bf2f(h0.w) * w0);
  }
  // overflow (normally 0 entries -> one scalar read)
  int novf = *ovfc;
  novf = novf < OVFCAP ? novf : OVFCAP;
  for (int k = 0; k < novf; ++k) {
    int4 e = ovf[k];
    if (e.x == dst) {
      short4 h0 = *(const short4*)(hp + (size_t)e.y * D);
      float w0 = __int_as_float(e.z);
      m[0][0] = fmaxf(m[0][0], bf2f(h0.x) * w0); m[0][1] = fmaxf(m[0][1], bf2f(h0.y) * w0);
      m[0][2] = fmaxf(m[0][2], bf2f(h0.z) * w0); m[0][3] = fmaxf(m[0][3], bf2f(h0.w) * w0);
    }
  }
#pragma unroll
  for (int j = 1; j < 8; ++j)
#pragma unroll
    for (int d2 = 0; d2 < 4; d2++) m[0][d2] = fmaxf(m[0][d2], m[j][d2]);
  short4 o;
  o.x = f2bf(m[0][0]); o.y = f2bf(m[0][1]);
  o.z = f2bf(m[0][2]); o.w = f2bf(m[0][3]);
  *(short4*)(agg + (size_t)dst * D + lane * 4) = o;
}

// ---- GEMM: out = relu( A1 @ W1 [+ A2 @ W2] + bias )
// Block = 64 rows x 256 cols, 4 waves. A1 fp32 (reg-staged: global->cvt->
// swizzled ds_write) or bf16 (global_load_lds DMA, inverse-swizzled source).
// A2 (if any) always bf16 via DMA. B pre-packed fragment-major, fully
// register-resident per wave. NSRC=1: 32KB LDS -> 4 blocks/CU for latency
// hiding; NSRC=2: 64KB LDS -> 2 blocks/CU.
template<typename TA1, int NSRC, int F32OUT>
__global__ __launch_bounds__(256, NSRC == 1 ? 4 : 2) void gemm_k(
    const TA1* __restrict__ A1, const short* __restrict__ B1p,
    const short* __restrict__ A2, const short* __restrict__ B2p,
    const float* __restrict__ bias, void* __restrict__ outp, int M)
{
  constexpr bool A1F = same_t<TA1, float>::v;
  __shared__ short smem[NSRC * 64 * 256];
  const int tid = threadIdx.x;
  const int wave = tid >> 6, lane = tid & 63;
  const int lr = lane & 15, kg = lane >> 4;
  const int m_base = blockIdx.x * 64;

  const short* Bs[2] = {B1p, B2p};

  // ---- DMA stages (issued first -> oldest in vmcnt FIFO)
  if constexpr (!A1F) {
#pragma unroll
    for (int it = 0; it < 8; ++it) {
      int L = it * 4096 + tid * 16;
      int row = L >> 9;
      int colb = (L & 511) ^ ((row & 7) << 4);
      int grow = m_base + row;
      grow = grow < M ? grow : M - 1;
      const char* gp = (const char*)A1 + (size_t)grow * 512 + colb;
      char* lp = (char*)smem + L;
      __builtin_amdgcn_global_load_lds((const glb_v*)gp, (lds_v*)lp, 16, 0, 0);
    }
  }
  if constexpr (NSRC == 2) {
#pragma unroll
    for (int it = 0; it < 8; ++it) {
      int L = it * 4096 + tid * 16;
      int row = L >> 9;
      int colb = (L & 511) ^ ((row & 7) << 4);
      int grow = m_base + row;
      grow = grow < M ? grow : M - 1;
      const char* gp = (const char*)A2 + (size_t)grow * 512 + colb;
      char* lp = (char*)smem + 32768 + L;
      __builtin_amdgcn_global_load_lds((const glb_v*)gp, (lds_v*)lp, 16, 0, 0);
    }
  }
  __builtin_amdgcn_sched_barrier(0);

  // ---- fp32 A1: reg-stage (16 independent loads, cvt, swizzled ds_write)
  if constexpr (A1F) {
    float4 fa[8][2];
#pragma unroll
    for (int it = 0; it < 8; ++it) {
      int L = it * 4096 + tid * 16;
      int row = L >> 9;
      int colel = (L & 511) >> 1;       // bf16 element index in row
      int grow = m_base + row;
      grow = grow < M ? grow : M - 1;
      const float* gp = A1 + (size_t)grow * D + colel;
      fa[it][0] = *(const float4*)gp;
      fa[it][1] = *(const float4*)(gp + 4);
    }
#pragma unroll
    for (int it = 0; it < 8; ++it) {
      int L = it * 4096 + tid * 16;
      int row = L >> 9;
      int Lw = L ^ ((row & 7) << 4);    // swizzled dest
      s16x8 o;
      o[0] = f2bf(fa[it][0].x); o[1] = f2bf(fa[it][0].y);
      o[2] = f2bf(fa[it][0].z); o[3] = f2bf(fa[it][0].w);
      o[4] = f2bf(fa[it][1].x); o[5] = f2bf(fa[it][1].y);
      o[6] = f2bf(fa[it][1].z); o[7] = f2bf(fa[it][1].w);
      *(s16x8*)((char*)smem + Lw) = o;
    }
    __builtin_amdgcn_sched_barrier(0);
  }

  f32x4 acc[4][4];
#pragma unroll
  for (int t = 0; t < 4; t++)
#pragma unroll
    for (int u = 0; u < 4; u++) acc[t][u] = (f32x4)(0.0f);

#pragma unroll
  for (int s = 0; s < NSRC; ++s) {
    // B panel resident: 32 coalesced 16B loads
    s16x8 breg[4][8];
#pragma unroll
    for (int u = 0; u < 4; ++u)
#pragma unroll
      for (int kc = 0; kc < 8; ++kc) {
        int g16 = wave * 4 + u;
        breg[u][kc] = *(const s16x8*)(Bs[s] + ((size_t)((g16 * 8 + kc) * 64 + lane)) * 8);
      }
    if (s == 0) {
      if constexpr (A1F && NSRC == 1) {
        // only ds_writes to drain; B loads stay in flight
        asm volatile("s_waitcnt lgkmcnt(0)" ::: "memory");
        __builtin_amdgcn_s_barrier();
        __builtin_amdgcn_sched_barrier(0);
      } else if constexpr (A1F && NSRC == 2) {
        __syncthreads();                 // drain DMA (vmcnt 0) + ds_writes
        __builtin_amdgcn_sched_barrier(0);
      } else {
        // DMAs (8*NSRC) are oldest; done when <=32 (B loads) outstanding
        asm volatile("s_waitcnt vmcnt(32)" ::: "memory");
        __builtin_amdgcn_s_barrier();
        __builtin_amdgcn_sched_barrier(0);
      }
    }
#pragma unroll
    for (int kc = 0; kc < 8; ++kc) {
      s16x8 a[4];
#pragma unroll
      for (int t = 0; t < 4; ++t) {
        int row = t * 16 + lr;
        int base = (row << 9) + kc * 64 + kg * 16;
        int off = s * 32768 + (base ^ ((row & 7) << 4));
        a[t] = *(const s16x8*)((const char*)smem + off);
      }
#pragma unroll
      for (int t = 0; t < 4; ++t)
#pragma unroll
        for (int u = 0; u < 4; ++u)
          acc[t][u] = __builtin_amdgcn_mfma_f32_16x16x32_bf16(a[t], breg[u][kc], acc[t][u], 0, 0, 0);
    }
  }

  // ---- epilogue: D layout col=lane&15, row=(lane>>4)*4+i
#pragma unroll
  for (int t = 0; t < 4; ++t) {
    int grow0 = m_base + t * 16 + kg * 4;
    if (m_base + t * 16 < M) {
#pragma unroll
      for (int u = 0; u < 4; ++u) {
        int col = wave * 64 + u * 16 + lr;
        float bv = bias[col];
#pragma unroll
        for (int i = 0; i < 4; ++i) {
          float v = acc[t][u][i] + bv;
          v = v > 0.0f ? v : 0.0f;
          size_t idx = (size_t)(grow0 + i) * D + col;
          if (F32OUT) ((float*)outp)[idx] = v;
          else        ((short*)outp)[idx] = f2bf(v);
        }
      }
    }
  }
}

// ---- FUSED layer-1 dst GEMM + layer-2 pre GEMM:
//   l1o = relu( X @ Ws1 + agg1 @ Wn1 + b1 )   [write only rows < LROWS]
//   h2  = relu( l1o @ Wp2 + bp2 )
__global__ __launch_bounds__(256, 2) void gemm23_k(
    const float* __restrict__ X, const short* __restrict__ Bs1,
    const short* __restrict__ A2, const short* __restrict__ Bn1,
    const short* __restrict__ Bp2,
    const float* __restrict__ b1, const float* __restrict__ bp2,
    short* __restrict__ l1o, short* __restrict__ h2, int M, int LROWS)
{
  __shared__ short smem[2 * 64 * 256];
  const int tid = threadIdx.x;
  const int wave = tid >> 6, lane = tid & 63;
  const int lr = lane & 15, kg = lane >> 4;
  const int m_base = blockIdx.x * 64;

  const short* Bs[2] = {Bs1, Bn1};

  // DMA agg1 tile -> smem[1]
#pragma unroll
  for (int it = 0; it < 8; ++it) {
    int L = it * 4096 + tid * 16;
    int row = L >> 9;
    int colb = (L & 511) ^ ((row & 7) << 4);
    int grow = m_base + row;
    grow = grow < M ? grow : M - 1;
    const char* gp = (const char*)A2 + (size_t)grow * 512 + colb;
    char* lp = (char*)smem + 32768 + L;
    __builtin_amdgcn_global_load_lds((const glb_v*)gp, (lds_v*)lp, 16, 0, 0);
  }
  __builtin_amdgcn_sched_barrier(0);

  // fp32 X reg-stage -> smem[0]
  {
    float4 fa[8][2];
#pragma unroll
    for (int it = 0; it < 8; ++it) {
      int L = it * 4096 + tid * 16;
      int row = L >> 9;
      int colel = (L & 511) >> 1;
      int grow = m_base + row;
      grow = grow < M ? grow : M - 1;
      const float* gp = X + (size_t)grow * D + colel;
      fa[it][0] = *(const float4*)gp;
      fa[it][1] = *(const float4*)(gp + 4);
    }
#pragma unroll
    for (int it = 0; it < 8; ++it) {
      int L = it * 4096 + tid * 16;
      int row = L >> 9;
      int Lw = L ^ ((row & 7) << 4);
      s16x8 o;
      o[0] = f2bf(fa[it][0].x); o[1] = f2bf(fa[it][0].y);
      o[2] = f2bf(fa[it][0].z); o[3] = f2bf(fa[it][0].w);
      o[4] = f2bf(fa[it][1].x); o[5] = f2bf(fa[it][1].y);
      o[6] = f2bf(fa[it][1].z); o[7] = f2bf(fa[it][1].w);
      *(s16x8*)((char*)smem + Lw) = o;
    }
    __builtin_amdgcn_sched_barrier(0);
  }

  f32x4 acc[4][4];
#pragma unroll
  for (int t = 0; t < 4; t++)
#pragma unroll
    for (int u = 0; u < 4; u++) acc[t][u] = (f32x4)(0.0f);

#pragma unroll
  for (int s = 0; s < 2; ++s) {
    s16x8 breg[4][8];
#pragma unroll
    for (int u = 0; u < 4; ++u)
#pragma unroll
      for (int kc = 0; kc < 8; ++kc) {
        int g16 = wave * 4 + u;
        breg[u][kc] = *(const s16x8*)(Bs[s] + ((size_t)((g16 * 8 + kc) * 64 + lane)) * 8);
      }
    if (s == 0) {
      __syncthreads();                 // drain DMA + ds_writes
      __builtin_amdgcn_sched_barrier(0);
    }
#pragma unroll
    for (int kc = 0; kc < 8; ++kc) {
      s16x8 a[4];
#pragma unroll
      for (int t = 0; t < 4; ++t) {
        int row = t * 16 + lr;
        int base = (row << 9) + kc * 64 + kg * 16;
        int off = s * 32768 + (base ^ ((row & 7) << 4));
        a[t] = *(const s16x8*)((const char*)smem + off);
      }
#pragma unroll
      for (int t = 0; t < 4; ++t)
#pragma unroll
        for (int u = 0; u < 4; ++u)
          acc[t][u] = __builtin_amdgcn_mfma_f32_16x16x32_bf16(a[t], breg[u][kc], acc[t][u], 0, 0, 0);
    }
  }

  // all waves done reading smem -> safe to reuse smem[0] for l1o tile
  __builtin_amdgcn_s_barrier();
  __builtin_amdgcn_sched_barrier(0);

  // issue Wp2 panel loads (in flight across epilogue-1)
  s16x8 breg2[4][8];
#pragma unroll
  for (int u = 0; u < 4; ++u)
#pragma unroll
    for (int kc = 0; kc < 8; ++kc) {
      int g16 = wave * 4 + u;
      breg2[u][kc] = *(const s16x8*)(Bp2 + ((size_t)((g16 * 8 + kc) * 64 + lane)) * 8);
    }

  // epilogue-1: l1o = relu(acc+b1); global write (rows<LROWS) + LDS write
#pragma unroll
  for (int t = 0; t < 4; ++t)
#pragma unroll
    for (int u = 0; u < 4; ++u) {
      int col = wave * 64 + u * 16 + lr;
      float bv = b1[col];
#pragma unroll
      for (int i = 0; i < 4; ++i) {
        int r = t * 16 + kg * 4 + i;   // block-local row
        float v = acc[t][u][i] + bv;
        v = v > 0.0f ? v : 0.0f;
        short sv = f2bf(v);
        int grow = m_base + r;
        if (grow < LROWS) l1o[(size_t)grow * D + col] = sv;
        int ba = ((r << 9) + 2 * col) ^ ((r & 7) << 4);
        *(short*)((char*)smem + ba) = sv;
      }
    }
  asm volatile("s_waitcnt lgkmcnt(0)" ::: "memory");
  __builtin_amdgcn_s_barrier();
  __builtin_amdgcn_sched_barrier(0);

  // stage-2: h2 = relu(l1o @ Wp2 + bp2)
  f32x4 acc2[4][4];
#pragma unroll
  for (int t = 0; t < 4; t++)
#pragma unroll
    for (int u = 0; u < 4; u++) acc2[t][u] = (f32x4)(0.0f);
#pragma unroll
  for (int kc = 0; kc < 8; ++kc) {
    s16x8 a[4];
#pragma unroll
    for (int t = 0; t < 4; ++t) {
      int row = t * 16 + lr;
      int base = (row << 9) + kc * 64 + kg * 16;
      int off = base ^ ((row & 7) << 4);
      a[t] = *(const s16x8*)((const char*)smem + off);
    }
#pragma unroll
    for (int t = 0; t < 4; ++t)
#pragma unroll
      for (int u = 0; u < 4; ++u)
        acc2[t][u] = __builtin_amdgcn_mfma_f32_16x16x32_bf16(a[t], breg2[u][kc], acc2[t][u], 0, 0, 0);
  }

#pragma unroll
  for (int t = 0; t < 4; ++t) {
    int grow0 = m_base + t * 16 + kg * 4;
    if (m_base + t * 16 < M) {
#pragma unroll
      for (int u = 0; u < 4; ++u) {
        int col = wave * 64 + u * 16 + lr;
        float bv = bp2[col];
#pragma unroll
        for (int i = 0; i < 4; ++i) {
          float v = acc2[t][u][i] + bv;
          v = v > 0.0f ? v : 0.0f;
          h2[(size_t)(grow0 + i) * D + col] = f2bf(v);
        }
      }
    }
  }
}

extern "C" void kernel_launch(void* const* d_in, const int* in_sizes, int n_in,
                              void* d_out, int out_size, void* d_ws, size_t ws_size,
                              hipStream_t stream)
{
  const float* x    = (const float*)d_in[0];
  const int*   src0 = (const int*)d_in[1];
  const int*   dst0 = (const int*)d_in[2];
  const float* w0   = (const float*)d_in[3];
  const int*   src1 = (const int*)d_in[4];
  const int*   dst1 = (const int*)d_in[5];
  const float* w1   = (const float*)d_in[6];
  const float* Wp1  = (const float*)d_in[7];
  const float* bp1  = (const float*)d_in[8];
  const float* Ws1  = (const float*)d_in[9];
  const float* Wn1  = (const float*)d_in[10];
  const float* b1   = (const float*)d_in[11];
  const float* Wp2  = (const float*)d_in[12];
  const float* bp2  = (const float*)d_in[13];
  const float* Ws2  = (const float*)d_in[14];
  const float* Wn2  = (const float*)d_in[15];
  const float* b2   = (const float*)d_in[16];

  const int E0 = in_sizes[1], E1 = in_sizes[4];
  const int NCTR = N1C + N2C + 2;   // cur0, cur1, ovfc0, ovfc1

  char* ws = (char*)d_ws;
  size_t off = 0;
  auto alloc = [&](size_t bytes) {
    void* p = ws + off;
    off += (bytes + 255) & ~(size_t)255;
    return p;
  };
  short* wp1t = (short*)alloc((size_t)D * D * 2);
  short* ws1t = (short*)alloc((size_t)D * D * 2);
  short* wn1t = (short*)alloc((size_t)D * D * 2);
  short* wp2t = (short*)alloc((size_t)D * D * 2);
  short* ws2t = (short*)alloc((size_t)D * D * 2);
  short* wn2t = (short*)alloc((size_t)D * D * 2);
  short* h1   = (short*)alloc((size_t)N0C * D * 2);
  short* h2   = (short*)alloc((size_t)N1C * D * 2);
  short* l1o  = (short*)alloc((size_t)N2C * D * 2);   // only first 4000 rows needed
  short* agg1 = (short*)alloc((size_t)N1C * D * 2);
  short* agg2 = (short*)alloc((size_t)N2C * D * 2);
  int*   ctrs = (int*)alloc((size_t)NCTR * 4);   // one contiguous block
  int*   cur0 = ctrs;
  int*   cur1 = ctrs + N1C;
  int*   ovfc0 = ctrs + N1C + N2C;
  int*   ovfc1 = ctrs + N1C + N2C + 1;
  int2*  rec0 = (int2*)alloc((size_t)N1C * BCAP * 8);
  int2*  rec1 = (int2*)alloc((size_t)N2C * BCAP * 8);
  int4*  ovf0 = (int4*)alloc((size_t)OVFCAP * 16);
  int4*  ovf1 = (int4*)alloc((size_t)OVFCAP * 16);

  // weights -> fragment-major bf16; also zeroes counters (49152 thr >= NCTR)
  wtransp_k<<<dim3(32, 6), 256, 0, stream>>>(Wp1, Ws1, Wn1, Wp2, Ws2, Wn2,
                                             wp1t, ws1t, wn1t, wp2t, ws2t, wn2t,
                                             ctrs, NCTR);

  int eb = (E0 + E1 + 255) / 256;
  scat_direct_k<<<eb, 256, 0, stream>>>(src0, dst0, w0, E0, cur0, rec0, ovfc0, ovf0,
                                        src1, dst1, w1, E1, cur1, rec1, ovfc1, ovf1);

  // h1 = relu(x @ Wp1 + bp1) -> bf16   (A = fp32 x, reg-staged cvt)
  gemm_k<float, 1, 0><<<(N0C + 63) / 64, 256, 0, stream>>>(
      x, wp1t, (const short*)nullptr, nullptr, bp1, h1, N0C);
  // agg1 = segment_max(h1[src0]*w0, dst0) -> bf16
  seg_max_k<<<(N1C + 3) / 4, 256, 0, stream>>>(h1, cur0, rec0, ovfc0, ovf0, agg1, N1C);
  // FUSED: l1o = relu(x@Ws1 + agg1@Wn1 + b1) [rows<4000 to HBM]
  //        h2  = relu(l1o @ Wp2 + bp2)
  gemm23_k<<<(N1C + 63) / 64, 256, 0, stream>>>(
      x, ws1t, agg1, wn1t, wp2t, b1, bp2, l1o, h2, N1C, N2C);
  // agg2 = segment_max(h2[src1]*w1, dst1) -> bf16
  seg_max_k<<<(N2C + 3) / 4, 256, 0, stream>>>(h2, cur1, rec1, ovfc1, ovf1, agg2, N2C);
  // out = relu(l1o[:N2] @ Ws2 + agg2 @ Wn2 + b2) -> fp32
  gemm_k<short, 2, 1><<<(N2C + 63) / 64, 256, 0, stream>>>(
      l1o, ws2t, agg2, wn2t, b2, d_out, N2C);
}